// Round 10
// baseline (804.874 us; speedup 1.0000x reference)
//
#include <hip/hip_runtime.h>
#include <hip/hip_bf16.h>

// ---------------------------------------------------------------------------
// THEGCNModel — R26 (two-pass bucketed scatter):
//   * R22/R24/R25 post-mortems: scatter is bound by partial-line writes to
//     srcdtS (WRITE 72-100MB vs 12.8 ideal; FETCH includes the RMW reads).
//     Reads were L3-absorbed all along. Fix: bucket sort.
//     Pass 1 (k_bucket): LDS-ranked per-block contiguous chunk writes into
//     the final dst-group regions (amp~1). Pass 2 (k_scatter2): per
//     XCD-group, sequential 2.4MB bucket read + scatter into its 1.6MB
//     L2-resident srcdtS window. Bucket buffer overlays uni (stream-ordered,
//     dead before prep_all).
//   * bktBase/bktCur (8+8 ints) captured in k_expand_add at the exact
//     group boundaries rowPtr[N*g/8] — capacity exact by construction.
//   * Everything else identical to R22 (796us known-good).
// ---------------------------------------------------------------------------

typedef float  f32x4 __attribute__((ext_vector_type(4)));
typedef short  s16x8 __attribute__((ext_vector_type(8)));
typedef int    i32x4 __attribute__((ext_vector_type(4)));

__device__ __forceinline__ float tanh_factor(float u) {
  // 2*tanh(u)-1 == 1 - 4/(exp(2u)+1); rcp is 1-ulp approx (noise vs bf16)
  float e = __expf(2.0f * u);
  return fmaf(-4.0f, __builtin_amdgcn_rcpf(e + 1.0f), 1.0f);
}

__device__ __forceinline__ void atomic_add_f32(float* p, float v) {
  unsafeAtomicAdd(p, v);               // native global_atomic_add_f32
}

__device__ __forceinline__ unsigned short f2bf(float f) {
  __hip_bfloat16 b = __float2bfloat16(f);
  return *(unsigned short*)&b;
}
__device__ __forceinline__ float bf2f(unsigned short u) {
  unsigned int v = ((unsigned int)u) << 16;
  return *(float*)&v;
}

// ---------------------------------------------------------------------------
// Counting sort by dst: histogram -> scan -> expand(dstS) -> bucket -> scatter.
// ---------------------------------------------------------------------------
__global__ __launch_bounds__(256) void k_hist(
    const int* __restrict__ ei, int* __restrict__ cntI, int E)
{
  int e = blockIdx.x * 256 + threadIdx.x;
  if (e < E) atomicAdd(&cntI[__builtin_nontemporal_load(ei + E + e)], 1);
}

__global__ __launch_bounds__(256) void k_scan_block(
    const int* __restrict__ cntI, int* __restrict__ cursor,
    int* __restrict__ bsum, int N)
{
  __shared__ int s[256];
  const int t = threadIdx.x;
  int i = blockIdx.x * 256 + t;
  int v = (i < N) ? cntI[i] : 0;
  s[t] = v;
  for (int off = 1; off < 256; off <<= 1) {
    __syncthreads();
    int x = (t >= off) ? s[t - off] : 0;
    __syncthreads();
    s[t] += x;
  }
  __syncthreads();
  if (i < N) cursor[i] = s[t] - v;          // local exclusive
  if (t == 255) bsum[blockIdx.x] = s[255];
}

__global__ __launch_bounds__(512) void k_scan_bsum(int* __restrict__ bsum, int nb)
{
  __shared__ int s[512];
  const int t = threadIdx.x;
  int v = (t < nb) ? bsum[t] : 0;
  s[t] = v;
  for (int off = 1; off < 512; off <<= 1) {
    __syncthreads();
    int x = (t >= off) ? s[t - off] : 0;
    __syncthreads();
    s[t] += x;
  }
  __syncthreads();
  if (t < nb) bsum[t] = s[t] - v;           // exclusive
}

// fused: cursor += block offset (final rowPtr), expand dstS runs, AND capture
// bucket boundaries bktBase/bktCur[g] = rowPtr[N*g/8].
__global__ __launch_bounds__(256) void k_expand_add(
    int* __restrict__ cursor, const int* __restrict__ bsum,
    const int* __restrict__ cntI, int* __restrict__ dstS,
    int* __restrict__ bktBase, int* __restrict__ bktCur, int N)
{
  int n = blockIdx.x * 256 + threadIdx.x;
  if (n >= N) return;
  int cur = cursor[n] + bsum[blockIdx.x];
  cursor[n] = cur;
#pragma unroll
  for (int g = 0; g < 8; g++) {
    int log = (int)(((long long)N * g) >> 3);
    if (n == log) { bktBase[g] = cur; bktCur[g] = cur; }
  }
  int c = cntI[n];
  for (int i = 0; i < c; i++) dstS[cur + i] = n;
}

// Pass 1: bucket edges by dst-group into the final group regions.
// Per-block LDS ranks -> one global atomic per bucket per block ->
// CONTIGUOUS chunk writes (write-amp ~1).
__global__ __launch_bounds__(256) void k_bucket(
    const int* __restrict__ ei, const float* __restrict__ dts,
    int* __restrict__ bktCur, int* __restrict__ bdst,
    int2* __restrict__ bsd, int E, int N)
{
  __shared__ int lcnt[8], lbase[8];
  const int t = threadIdx.x;
  int lo[7];
#pragma unroll
  for (int g = 1; g < 8; g++) lo[g - 1] = (int)(((long long)N * g) >> 3);

  const int E4 = (E + 3) >> 2;
  for (int b4 = blockIdx.x * 256; b4 < E4; b4 += gridDim.x * 256) {
    int e4 = b4 + t;
    int d[4], s[4], tv[4], g4[4];
    bool ok[4];
    int e0 = e4 << 2;
    if (e4 < E4 && e0 + 3 < E) {
      i32x4 dv = __builtin_nontemporal_load((const i32x4*)(ei + E) + e4);
      i32x4 sv = __builtin_nontemporal_load((const i32x4*)ei + e4);
      i32x4 tw = __builtin_nontemporal_load((const i32x4*)dts + e4);
#pragma unroll
      for (int j = 0; j < 4; j++) {
        d[j] = dv[j]; s[j] = sv[j]; tv[j] = tw[j]; ok[j] = true;
      }
    } else {
#pragma unroll
      for (int j = 0; j < 4; j++) {
        int e = e0 + j;
        ok[j] = (e4 < E4) && (e < E);
        d[j]  = ok[j] ? ei[E + e] : 0;
        s[j]  = ok[j] ? ei[e] : 0;
        tv[j] = ok[j] ? __float_as_int(dts[e]) : 0;
      }
    }
#pragma unroll
    for (int j = 0; j < 4; j++) {
      int g = 0;
#pragma unroll
      for (int k = 0; k < 7; k++) g += (d[j] >= lo[k]);
      g4[j] = g;
    }
    if (t < 8) lcnt[t] = 0;
    __syncthreads();
    int rank[4];
#pragma unroll
    for (int j = 0; j < 4; j++)
      rank[j] = ok[j] ? atomicAdd(&lcnt[g4[j]], 1) : 0;
    __syncthreads();
    if (t < 8) lbase[t] = lcnt[t] ? atomicAdd(&bktCur[t], lcnt[t]) : 0;
    __syncthreads();
#pragma unroll
    for (int j = 0; j < 4; j++) {
      if (ok[j]) {
        int pos = lbase[g4[j]] + rank[j];
        bdst[pos] = d[j];
        bsd[pos]  = make_int2(s[j], tv[j]);
      }
    }
    __syncthreads();   // lcnt reset next iteration
  }
}

// Pass 2: per XCD-group scatter within its L2-resident srcdtS window.
__global__ __launch_bounds__(256) void k_scatter2(
    const int* __restrict__ bktBase, const int* __restrict__ bdst,
    const int2* __restrict__ bsd, int* __restrict__ cursor,
    int2* __restrict__ srcdtS, int E)
{
  const int g  = blockIdx.x & 7;
  const int bi = blockIdx.x >> 3;
  const int nb = gridDim.x >> 3;
  const int beg = bktBase[g];
  const int end = (g < 7) ? bktBase[g + 1] : E;
  for (int i = beg + bi * 256 + threadIdx.x; i < end; i += nb * 256) {
    int d   = bdst[i];
    int2 sd = bsd[i];
    int pos = atomicAdd(&cursor[d], 1);
    srcdtS[pos] = sd;
  }
}

// ---------------------------------------------------------------------------
// prep_all: xb = bf16(x) padded to 24 cols; phase-1 weights W1t1/W2t1; phase-2
// weights W1t/W2t; classifier weights cW1t/cW2t; zeroes acc1 (N*17 f32) and
// bnsAll (512 f32).
// ---------------------------------------------------------------------------
__global__ __launch_bounds__(256) void prep_all(
    const float* __restrict__ x, const float* __restrict__ tW1,
    const float* __restrict__ tW2, const float* __restrict__ sW1,
    const float* __restrict__ sW2, const float* __restrict__ cW1,
    const float* __restrict__ cW2, unsigned short* __restrict__ xb,
    unsigned short* __restrict__ W1t1, unsigned short* __restrict__ W2t1,
    unsigned short* __restrict__ W1t, unsigned short* __restrict__ W2t,
    unsigned short* __restrict__ cW1t, unsigned short* __restrict__ cW2t,
    float* __restrict__ acc1, float* __restrict__ bnsAll, int N)
{
  int i = blockIdx.x * 256 + threadIdx.x;
  int totalX = N * 24;
  for (int idx = i; idx < totalX; idx += gridDim.x * 256) {
    int n = idx / 24, c = idx - n * 24;
    xb[idx] = (c < 17) ? f2bf(x[n * 17 + c]) : (unsigned short)0;
  }
  // zero acc1 (N*17) + bnsAll (512)
  for (int idx = i; idx < N * 17; idx += gridDim.x * 256) acc1[idx] = 0.0f;
  if (i < 512) bnsAll[i] = 0.0f;
  if (i < 48 * 96) {
    int n = i / 96, k = i - n * 96;
    int src = (k < 17) ? k : (k >= 24 && k < 41) ? (k - 24 + 17)
            : (k >= 48 && k < 80) ? (k - 48 + 34) : -1;
    W1t1[i] = (n < 33 && src >= 0) ? f2bf(tW1[src * 33 + n]) : (unsigned short)0;
  }
  if (i < 32 * 64) {
    int n = i / 64, k = i - n * 64;
    W2t1[i] = (n < 17 && k < 33) ? f2bf(tW2[k * 17 + n]) : (unsigned short)0;
  }
  if (i < 2 * 64 * 128) {
    int l = i >> 13; int r = i & 8191; int n = r >> 7; int k = r & 127;
    W1t[i] = f2bf(sW1[((size_t)l * 128 + k) * 64 + n]);
  }
  if (i < 2 * 64 * 64) {
    int l = i >> 12; int r = i & 4095; int n = r >> 6; int k = r & 63;
    W2t[i] = f2bf(sW2[((size_t)l * 64 + k) * 64 + n]);
  }
  if (i < 64 * 64) {
    int c = i >> 6, k = i & 63;
    cW1t[i] = f2bf(cW1[k * 64 + c]);
  }
  if (i < 32 * 64) {
    int c = i >> 6, k = i & 63;
    cW2t[i] = f2bf(cW2[k * 32 + c]);
  }
}

// ---------------------------------------------------------------------------
// Phase 1 edge kernel (MFMA, barrier-free wave-private 16-edge tiles).
// R22: R19 body (2-deep prefetch: idx(t+2)/payload(t+1)) at the low-FETCH
// config 768/(256,3).
// ---------------------------------------------------------------------------
__global__ __launch_bounds__(256, 3) void phase1_edge_mfma(
    const unsigned short* __restrict__ xb, const int* __restrict__ dstS,
    const int2* __restrict__ srcdtS, const float* __restrict__ freq,
    const float* __restrict__ phs,
    const unsigned short* __restrict__ W1t1, const float* __restrict__ b1,
    const unsigned short* __restrict__ W2t1, const float* __restrict__ b2,
    float* __restrict__ accum, int E, int nwt)
{
  __shared__ unsigned short sA[64][104];
  __shared__ unsigned short sHid[64][72];
  __shared__ float sRed[64][20];
  __shared__ int   sDst[64];

  const int t = threadIdx.x;
  const int wv = t >> 6, lane = t & 63, l16 = lane & 15, quad = lane >> 4;
  const int r0 = wv * 16;
  const int e_loc = lane >> 2, q = lane & 3;
  const int rr = r0 + e_loc;

  s16x8 w1f[3][3], w2f[2][2];
  float bias1[3], bias2[2];
#pragma unroll
  for (int cb = 0; cb < 3; cb++) {
    int n = cb * 16 + l16;
#pragma unroll
    for (int kb = 0; kb < 3; kb++)
      w1f[cb][kb] = *(const s16x8*)&W1t1[n * 96 + kb * 32 + quad * 8];
    bias1[cb] = (n < 33) ? b1[n] : 0.0f;
  }
#pragma unroll
  for (int cb = 0; cb < 2; cb++) {
    int n = cb * 16 + l16;
#pragma unroll
    for (int kb = 0; kb < 2; kb++)
      w2f[cb][kb] = *(const s16x8*)&W2t1[n * 64 + kb * 32 + quad * 8];
    bias2[cb] = (n < 17) ? b2[n] : 0.0f;
  }

  // loop-invariant rel coefficients: this lane covers k = q*8 .. q*8+7
  float frq[8], phv[8];
#pragma unroll
  for (int j = 0; j < 8; j++) {
    frq[j] = freq[q * 8 + j];
    phv[j] = phs[q * 8 + j];
  }

  // zero own-wave pad columns once
  for (int i = lane; i < 16 * 28; i += 64) {
    int rrz = r0 + i / 28, c = i % 28;
    int col = (c < 6) ? 18 + c : (c < 12) ? 42 + (c - 6) : 80 + (c - 12);
    sA[rrz][col] = 0;
  }
  for (int i = lane; i < 256; i += 64)
    sHid[r0 + (i >> 4)][48 + (i & 15)] = 0;

  // XCD dst-range tiling: group g = blockIdx&7 owns [nwt*g/8, nwt*(g+1)/8).
  const int g8   = blockIdx.x & 7;
  const int tLo  = (int)(((long long)nwt * g8) >> 3);
  const int tHi  = (int)(((long long)nwt * (g8 + 1)) >> 3);
  const int wLoc = (blockIdx.x >> 3) * 4 + wv;
  const int nwLoc = (gridDim.x >> 3) * 4;

  // -- 2-deep pipeline: idx for tile t+1 (idxN/dtN), payload for tile t --
  int idxN = 0; float dtN = 0.0f;
  int ndP = 0; uint4 xa0, xa1; unsigned int xa2 = 0; float dtP = 0.0f;
  auto issue_idx = [&](int tt) {
    int er = (tt << 4) + e_loc; if (er >= E) er = E - 1;
    int2 sd = srcdtS[er];
    idxN = q ? sd.x : dstS[er];
    dtN  = __int_as_float(sd.y);
  };
  auto issue_payload = [&]() {           // consumes idxN/dtN already in regs
    ndP = idxN; dtP = dtN;
    if (q < 2) {
      const unsigned short* src = &xb[(size_t)ndP * 24];
      xa0 = *(const uint4*)&src[0];
      xa1 = *(const uint4*)&src[8];
      xa2 = *(const unsigned int*)&src[16];
    }
  };
  {
    int t0 = tLo + wLoc; if (t0 >= nwt) t0 = nwt - 1;
    issue_idx(t0);
    issue_payload();
    int t1 = t0 + nwLoc; if (t1 >= tHi) t1 = t0;
    issue_idx(t1);
  }

  for (int tile = tLo + wLoc; tile < tHi; tile += nwLoc) {
    const int eb = tile << 4;

    // stage pipelined regs -> LDS (own rows only; same-wave ordering)
    if (q < 2) {
      if (!q) sDst[rr] = ndP;
      const int base = q ? 24 : 0;
      *(uint4*)&sA[rr][base]     = xa0;
      *(uint4*)&sA[rr][base + 8] = xa1;
      *(unsigned int*)&sA[rr][base + 16] = xa2;
    }
    // all 64 lanes: 8 rel values each (k = q*8 + j) — no divergent half-wave
    {
      unsigned short tmp[8] __attribute__((aligned(16)));
#pragma unroll
      for (int j = 0; j < 8; j++)
        tmp[j] = f2bf(__cosf(fmaf(dtP, frq[j], phv[j])));
      *(uint4*)&sA[rr][48 + q * 8] = *(const uint4*)&tmp[0];
    }

    // payload gather for t+1 (index already resident — no dependent wait);
    // then index fetch for t+2. Both hide under pass1/pass2/tanh/walk.
    issue_payload();
    { int nt = tile + 2 * nwLoc; issue_idx(nt < tHi ? nt : tile); }

    // pass1: hid = relu(A @ W1 + b1)   (own row r0+l16)
    f32x4 a1[3];
#pragma unroll
    for (int cb = 0; cb < 3; cb++)
      a1[cb] = (f32x4){bias1[cb], bias1[cb], bias1[cb], bias1[cb]};
#pragma unroll
    for (int kb = 0; kb < 3; kb++) {
      s16x8 aF = *(const s16x8*)&sA[r0 + l16][kb * 32 + quad * 8];
#pragma unroll
      for (int cb = 0; cb < 3; cb++)
        a1[cb] = __builtin_amdgcn_mfma_f32_16x16x32_bf16(aF, w1f[cb][kb], a1[cb], 0, 0, 0);
    }
#pragma unroll
    for (int cb = 0; cb < 3; cb++)
#pragma unroll
      for (int reg = 0; reg < 4; reg++)
        sHid[r0 + quad * 4 + reg][cb * 16 + l16] = f2bf(fmaxf(a1[cb][reg], 0.0f));

    // pass2: u = hid @ W2 + b2
    f32x4 a2[2];
#pragma unroll
    for (int cb = 0; cb < 2; cb++)
      a2[cb] = (f32x4){bias2[cb], bias2[cb], bias2[cb], bias2[cb]};
#pragma unroll
    for (int kb = 0; kb < 2; kb++) {
      s16x8 aF = *(const s16x8*)&sHid[r0 + l16][kb * 32 + quad * 8];
#pragma unroll
      for (int cb = 0; cb < 2; cb++)
        a2[cb] = __builtin_amdgcn_mfma_f32_16x16x32_bf16(aF, w2f[cb][kb], a2[cb], 0, 0, 0);
    }

    // f -> sRed (own rows)
#pragma unroll
    for (int reg = 0; reg < 4; reg++) {
      int row = r0 + quad * 4 + reg;
      bool ok = (eb + quad * 4 + reg < E);
      sRed[row][l16] = ok ? tanh_factor(a2[0][reg]) : 0.0f;
      if (l16 == 0) sRed[row][16] = ok ? tanh_factor(a2[1][reg]) : 0.0f;
    }

    // wave-local segmented walk: lanes 0..16, col = lane, own 16 rows.
    if (lane < 17) {
      int col = lane;
      float run = 0.0f;
      int cur = __builtin_amdgcn_readfirstlane(sDst[r0]);
#pragma unroll
      for (int k = 0; k < 16; k++) {
        int d = __builtin_amdgcn_readfirstlane(sDst[r0 + k]);
        float v = sRed[r0 + k][col];
        if (d != cur) {
          atomic_add_f32(&accum[(size_t)cur * 17 + col], run);
          run = 0.0f; cur = d;
        }
        run += v;
      }
      atomic_add_f32(&accum[(size_t)cur * 17 + col], run);
    }
  }
}

// ---------------------------------------------------------------------------
// Phase 1 node kernel: h[n] = (x[n] * (1 + acc/max(cnt,1))) @ projW + projb.
// Also zeroes acc2 (replaces a 25.6MB memset dispatch).
// ---------------------------------------------------------------------------
__global__ __launch_bounds__(256) void phase1_node(
    const float* __restrict__ x, const float* __restrict__ acc1,
    const int* __restrict__ cntI, const float* __restrict__ Wp,
    const float* __restrict__ bp, float* __restrict__ h,
    float* __restrict__ acc2, int N)
{
  __shared__ float s0[4][20];
  const int t = threadIdx.x;
  const int nb = blockIdx.x << 2;
  if (t < 68) {
    int nl = t / 17, c = t % 17;
    int n = nb + nl;
    float v = 0.0f;
    if (n < N) {
      float cnt = fmaxf((float)cntI[n], 1.0f);
      v = x[n * 17 + c] * (1.0f + acc1[n * 17 + c] / cnt);
    }
    s0[nl][c] = v;
  }
  __syncthreads();
  int nl = t >> 6, j = t & 63;
  int n = nb + nl;
  if (n < N) {
    float acc = bp[j];
#pragma unroll
    for (int c = 0; c < 17; c++) acc = fmaf(s0[nl][c], Wp[c * 64 + j], acc);
    h[n * 64 + j] = acc;
    acc2[n * 64 + j] = 0.0f;
  }
}

// ---------------------------------------------------------------------------
// prep_P<DO_BN>: P1[n] = h'[n]@W1a + b1, P2[n] = h'[n]@W1b where
// h' = DO_BN ? relu(BN(h)) : h. DO_BN also writes h' back.
// ---------------------------------------------------------------------------
template <bool DO_BN>
__global__ void prep_P(
    float* __restrict__ h, const unsigned short* __restrict__ W1t,
    const float* __restrict__ b1,
    const float* __restrict__ bns, const float* __restrict__ bnq,
    const float* __restrict__ gam, const float* __restrict__ bet, float invR,
    unsigned short* __restrict__ P1, unsigned short* __restrict__ P2, int N)
{
  __shared__ unsigned short sH[64][72];
  __shared__ float sM[64], sS[64], sB[64];
  const int t = threadIdx.x;
  const int wv = t >> 6, lane = t & 63, l16 = lane & 15, quad = lane >> 4;
  const int nb = blockIdx.x << 6;

  if (DO_BN) {
    if (t < 64) {
      float m = bns[t] * invR;
      float var = bnq[t] * invR - m * m;
      sM[t] = m;
      sS[t] = gam[t] * rsqrtf(var + 1e-5f);
      sB[t] = bet[t];
    }
    __syncthreads();
  }

#pragma unroll
  for (int i = 0; i < 4; i++) {
    int g = t + i * 256;
    int r = g >> 4, c4 = (g & 15) << 2;
    int n0 = nb + r;
    bool valid = (n0 < N);
    int n = valid ? n0 : N - 1;
    float4 v = *(const float4*)&h[(size_t)n * 64 + c4];
    if (DO_BN) {
      v.x = fmaxf(fmaf(v.x - sM[c4 + 0], sS[c4 + 0], sB[c4 + 0]), 0.0f);
      v.y = fmaxf(fmaf(v.y - sM[c4 + 1], sS[c4 + 1], sB[c4 + 1]), 0.0f);
      v.z = fmaxf(fmaf(v.z - sM[c4 + 2], sS[c4 + 2], sB[c4 + 2]), 0.0f);
      v.w = fmaxf(fmaf(v.w - sM[c4 + 3], sS[c4 + 3], sB[c4 + 3]), 0.0f);
      if (valid) *(float4*)&h[(size_t)n0 * 64 + c4] = v;
    }
    ushort4 o = { f2bf(v.x), f2bf(v.y), f2bf(v.z), f2bf(v.w) };
    *(ushort4*)&sH[r][c4] = o;
  }
  __syncthreads();

  const int n = nb + wv * 16 + l16;
#pragma unroll
  for (int half = 0; half < 2; half++) {
    f32x4 acc[4];
#pragma unroll
    for (int cb = 0; cb < 4; cb++) {
      if (half == 0) {
        float4 bv = *(const float4*)&b1[cb * 16 + quad * 4];
        acc[cb] = (f32x4){bv.x, bv.y, bv.z, bv.w};
      } else {
        acc[cb] = (f32x4){0.0f, 0.0f, 0.0f, 0.0f};
      }
    }
#pragma unroll
    for (int kb = 0; kb < 2; kb++) {
      s16x8 bF = *(const s16x8*)&sH[wv * 16 + l16][kb * 32 + quad * 8];
#pragma unroll
      for (int cb = 0; cb < 4; cb++) {
        s16x8 aF = *(const s16x8*)&W1t[(cb * 16 + l16) * 128 + half * 64 + kb * 32 + quad * 8];
        acc[cb] = __builtin_amdgcn_mfma_f32_16x16x32_bf16(aF, bF, acc[cb], 0, 0, 0);
      }
    }
    if (n < N) {
      unsigned short* P = half ? P2 : P1;
#pragma unroll
      for (int cb = 0; cb < 4; cb++) {
        ushort4 o = { f2bf(acc[cb][0]), f2bf(acc[cb][1]),
                      f2bf(acc[cb][2]), f2bf(acc[cb][3]) };
        *(ushort4*)&P[(size_t)n * 64 + cb * 16 + quad * 4] = o;
      }
    }
  }
}

// ---------------------------------------------------------------------------
// Phase 2 edge kernel — barrier-free wave-private 16-edge tiles.
// R19 exact: bounds(256,5), grid 1280, 2-deep prefetch idx(t+2)/payload(t+1).
// ---------------------------------------------------------------------------
__global__ __launch_bounds__(256, 5) void phase2_edge(
    const unsigned short* __restrict__ P1, const unsigned short* __restrict__ P2,
    const int* __restrict__ dstS, const int2* __restrict__ srcdtS,
    const unsigned short* __restrict__ W2t, const float* __restrict__ b2,
    float* __restrict__ accum, int E, int nwt)
{
  __shared__ unsigned short sA[64][136];   // [edge][0:64]=P1[dst], [64:128]=P2[src]
  __shared__ int sDst[64];
  float* sRedF = (float*)&sA[0][0];        // aliased 64x68 f32 (same stride 272B)

  const int t = threadIdx.x;
  const int wv = t >> 6, lane = t & 63, l16 = lane & 15, quad = lane >> 4;
  const int r0 = wv * 16;

  s16x8 w2f[4][2];
  f32x4 bias2v[4];
#pragma unroll
  for (int cb = 0; cb < 4; cb++) {
#pragma unroll
    for (int kb = 0; kb < 2; kb++)
      w2f[cb][kb] = *(const s16x8*)&W2t[(cb * 16 + l16) * 64 + kb * 32 + quad * 8];
    float4 bv = *(const float4*)&b2[cb * 16 + quad * 4];
    bias2v[cb] = (f32x4){bv.x, bv.y, bv.z, bv.w};
  }

  const int eRow = r0 + l16;

  const int e_loc = lane >> 2, q = lane & 3;
  const int rr = r0 + e_loc;
  const unsigned short* const Pb = (q < 2) ? P1 : P2;
  const int cb0 = q * 32;
  const size_t sub = (size_t)((q & 1) * 32);

  // XCD dst-range tiling: group g = blockIdx&7 owns [nwt*g/8, nwt*(g+1)/8).
  const int g8   = blockIdx.x & 7;
  const int tLo  = (int)(((long long)nwt * g8) >> 3);
  const int tHi  = (int)(((long long)nwt * (g8 + 1)) >> 3);
  const int wLoc = (blockIdx.x >> 3) * 4 + wv;
  const int nwLoc = (gridDim.x >> 3) * 4;

  // -- 2-deep pipeline: idx for tile t+1, payload (64B row-quarter) for t --
  int idxN = 0;
  int ndP = 0; uint4 pA, pB, pC, pD;
  auto issue_idx = [&](int tt) {
    int er = (tt << 4) + e_loc; if (er >= E) er = E - 1;
    idxN = (q < 2) ? dstS[er] : srcdtS[er].x;
  };
  auto issue_payload = [&]() {           // consumes idxN already in regs
    ndP = idxN;
    const unsigned short* src = Pb + (size_t)ndP * 64 + sub;
    pA = *(const uint4*)&src[0];
    pB = *(const uint4*)&src[8];
    pC = *(const uint4*)&src[16];
    pD = *(const uint4*)&src[24];
  };
  {
    int t0 = tLo + wLoc; if (t0 >= nwt) t0 = nwt - 1;
    issue_idx(t0);
    issue_payload();
    int t1 = t0 + nwLoc; if (t1 >= tHi) t1 = t0;
    issue_idx(t1);
  }

  for (int tile = tLo + wLoc; tile < tHi; tile += nwLoc) {
    const int eb = tile << 4;

    // stage pipelined regs -> LDS (own rows only; same-wave ordering)
    if (q == 0) sDst[rr] = ndP;
    *(uint4*)&sA[rr][cb0]      = pA;
    *(uint4*)&sA[rr][cb0 + 8]  = pB;
    *(uint4*)&sA[rr][cb0 + 16] = pC;
    *(uint4*)&sA[rr][cb0 + 24] = pD;

    // payload gather for t+1 (index already resident), then idx for t+2.
    issue_payload();
    { int nt = tile + 2 * nwLoc; issue_idx(nt < tHi ? nt : tile); }

    // hidden B-frags: relu(P1+P2), packed bf16 (own row)
    s16x8 hidf[2];
#pragma unroll
    for (int kb = 0; kb < 2; kb++) {
      s16x8 x1 = *(const s16x8*)&sA[eRow][kb * 32 + quad * 8];
      s16x8 x2 = *(const s16x8*)&sA[eRow][64 + kb * 32 + quad * 8];
      s16x8 hf;
#pragma unroll
      for (int j = 0; j < 8; j++) {
        float a = bf2f((unsigned short)x1[j]);
        float b = bf2f((unsigned short)x2[j]);
        hf[j] = (short)f2bf(fmaxf(a + b, 0.0f));
      }
      hidf[kb] = hf;
    }

    // u^T[n2][edge] = W2t @ hidden^T + b2
    f32x4 acc[4];
#pragma unroll
    for (int cb = 0; cb < 4; cb++) acc[cb] = bias2v[cb];
#pragma unroll
    for (int kb = 0; kb < 2; kb++)
#pragma unroll
      for (int cb = 0; cb < 4; cb++)
        acc[cb] = __builtin_amdgcn_mfma_f32_16x16x32_bf16(w2f[cb][kb], hidf[kb], acc[cb], 0, 0, 0);

    // f = 2*tanh(u)-1 -> sRedF (own rows; same-wave ordering)
    bool ok = (eb + l16 < E);
#pragma unroll
    for (int cb = 0; cb < 4; cb++) {
      f32x4 f;
#pragma unroll
      for (int reg = 0; reg < 4; reg++)
        f[reg] = ok ? tanh_factor(acc[cb][reg]) : 0.0f;
      *(f32x4*)&sRedF[eRow * 68 + cb * 16 + quad * 4] = f;
    }

    // wave-local segmented walk: lane = col, own 16 rows.
    {
      float run = 0.0f;
      int cur = __builtin_amdgcn_readfirstlane(sDst[r0]);
#pragma unroll
      for (int k = 0; k < 16; k++) {
        int d = __builtin_amdgcn_readfirstlane(sDst[r0 + k]);
        float v = sRedF[(r0 + k) * 68 + lane];
        if (d != cur) {                       // scalar branch
          atomic_add_f32(&accum[(size_t)cur * 64 + lane], run);
          run = 0.0f; cur = d;
        }
        run += v;
      }
      atomic_add_f32(&accum[(size_t)cur * 64 + lane], run);
    }
  }
}

// ---------------------------------------------------------------------------
// Node update + BN statistics. ZERO: re-zero accum for the next layer
// (skipped on the last layer — saves a 25.6MB write).
// ---------------------------------------------------------------------------
template <bool ZERO>
__global__ __launch_bounds__(256) void node_update_bn(
    float* __restrict__ h, float* __restrict__ accum,
    const int* __restrict__ cntI, float* __restrict__ bns,
    float* __restrict__ bnq, int N)
{
  const int t = threadIdx.x;
  float ls = 0.0f, lq = 0.0f;
  int total = N * 64;
  for (int idx = blockIdx.x * 256 + t; idx < total; idx += gridDim.x * 256) {
    int n = idx >> 6;
    float cnt = fmaxf((float)cntI[n], 1.0f);
    float v = h[idx] * (1.0f + accum[idx] / cnt);
    if (ZERO) accum[idx] = 0.0f;       // ready for next layer's scatter
    h[idx] = v;
    ls += v; lq += v * v;
  }
  __shared__ float ss[256], sq[256];
  ss[t] = ls; sq[t] = lq;
  __syncthreads();
  if (t < 64) {
    float s = ss[t] + ss[t + 64] + ss[t + 128] + ss[t + 192];
    float q = sq[t] + sq[t + 64] + sq[t + 128] + sq[t + 192];
    atomic_add_f32(&bns[t], s);
    atomic_add_f32(&bnq[t], q);
  }
}

// ---------------------------------------------------------------------------
// Classifier MFMA with input-BN fused at staging.
// ---------------------------------------------------------------------------
template <int NCB>
__global__ __launch_bounds__(256) void clf_mfma(
    const float* __restrict__ in, const unsigned short* __restrict__ Wt,
    const float* __restrict__ bias, float* __restrict__ z,
    float* __restrict__ bns, float* __restrict__ bnq,
    const float* __restrict__ ibns, const float* __restrict__ ibnq,
    const float* __restrict__ igam, const float* __restrict__ ibet,
    float iinvR, int rows)
{
  __shared__ unsigned short sIn[64][72];
  __shared__ float sM[64], sS[64], sB[64];
  const int t = threadIdx.x;
  const int wv = t >> 6, lane = t & 63, l16 = lane & 15, quad = lane >> 4;
  const int nb = blockIdx.x << 6;

  if (t < 64) {
    float m = ibns[t] * iinvR;
    float var = ibnq[t] * iinvR - m * m;
    sM[t] = m;
    sS[t] = igam[t] * rsqrtf(var + 1e-5f);
    sB[t] = ibet[t];
  }

  s16x8 wf[NCB][2];
  f32x4 bv[NCB];
#pragma unroll
  for (int cb = 0; cb < NCB; cb++) {
#pragma unroll
    for (int kb = 0; kb < 2; kb++)
      wf[cb][kb] = *(const s16x8*)&Wt[(cb * 16 + l16) * 64 + kb * 32 + quad * 8];
    float4 b4 = *(const float4*)&bias[cb * 16 + quad * 4];
    bv[cb] = (f32x4){b4.x, b4.y, b4.z, b4.w};
  }
  __syncthreads();   // sM/sS/sB visible

#pragma unroll
  for (int i = 0; i < 4; i++) {
    int g = t + i * 256;
    int r = g >> 4, c4 = (g & 15) << 2;
    int n = nb + r; if (n >= rows) n = rows - 1;
    float4 v = *(const float4*)&in[(size_t)n * 64 + c4];
    v.x = fmaxf(fmaf(v.x - sM[c4 + 0], sS[c4 + 0], sB[c4 + 0]), 0.0f);
    v.y = fmaxf(fmaf(v.y - sM[c4 + 1], sS[c4 + 1], sB[c4 + 1]), 0.0f);
    v.z = fmaxf(fmaf(v.z - sM[c4 + 2], sS[c4 + 2], sB[c4 + 2]), 0.0f);
    v.w = fmaxf(fmaf(v.w - sM[c4 + 3], sS[c4 + 3], sB[c4 + 3]), 0.0f);
    ushort4 o = { f2bf(v.x), f2bf(v.y), f2bf(v.z), f2bf(v.w) };
    *(ushort4*)&sIn[r][c4] = o;
  }
  __syncthreads();

  const int n = nb + wv * 16 + l16;
  const bool ok = (n < rows);
  f32x4 acc[NCB];
#pragma unroll
  for (int cb = 0; cb < NCB; cb++) acc[cb] = bv[cb];
#pragma unroll
  for (int kb = 0; kb < 2; kb++) {
    s16x8 bF = *(const s16x8*)&sIn[wv * 16 + l16][kb * 32 + quad * 8];
#pragma unroll
    for (int cb = 0; cb < NCB; cb++)
      acc[cb] = __builtin_amdgcn_mfma_f32_16x16x32_bf16(wf[cb][kb], bF, acc[cb], 0, 0, 0);
  }

  // store z (f32) + per-col stats reduced over the wave's 16 rows
#pragma unroll
  for (int cb = 0; cb < NCB; cb++) {
    if (ok)
      *(float4*)&z[(size_t)n * (NCB * 16) + cb * 16 + quad * 4] =
          make_float4(acc[cb][0], acc[cb][1], acc[cb][2], acc[cb][3]);
    f32x4 s, q;
#pragma unroll
    for (int reg = 0; reg < 4; reg++) {
      float v = ok ? acc[cb][reg] : 0.0f;
      s[reg] = v; q[reg] = v * v;
    }
#pragma unroll
    for (int m = 1; m < 16; m <<= 1) {
#pragma unroll
      for (int reg = 0; reg < 4; reg++) {
        s[reg] += __shfl_xor(s[reg], m);
        q[reg] += __shfl_xor(q[reg], m);
      }
    }
    if (l16 == 0) {
#pragma unroll
      for (int reg = 0; reg < 4; reg++) {
        int col = cb * 16 + quad * 4 + reg;
        atomic_add_f32(&bns[col], s[reg]);
        atomic_add_f32(&bnq[col], q[reg]);
      }
    }
  }
}

// clf_final with fused input BN (slot stats over 32 cols).
__global__ __launch_bounds__(256) void clf_final(
    const float* __restrict__ z2, const float* __restrict__ W3,
    const float* __restrict__ b3,
    const float* __restrict__ ibns, const float* __restrict__ ibnq,
    const float* __restrict__ igam, const float* __restrict__ ibet,
    float iinvR, float* __restrict__ out, int rows)
{
  __shared__ float sM[32], sS[32], sB[32];
  const int t = threadIdx.x;
  if (t < 32) {
    float m = ibns[t] * iinvR;
    float var = ibnq[t] * iinvR - m * m;
    sM[t] = m;
    sS[t] = igam[t] * rsqrtf(var + 1e-5f);
    sB[t] = ibet[t];
  }
  __syncthreads();
  int n = blockIdx.x * 256 + t;
  if (n >= rows) return;
  float acc = b3[0];
#pragma unroll
  for (int k = 0; k < 32; k++) {
    float v = fmaxf(fmaf(z2[n * 32 + k] - sM[k], sS[k], sB[k]), 0.0f);
    acc = fmaf(v, W3[k], acc);
  }
  out[n] = acc;
}

// ---------------------------------------------------------------------------
extern "C" void kernel_launch(void* const* d_in, const int* in_sizes, int n_in,
                              void* d_out, int out_size, void* d_ws, size_t ws_size,
                              hipStream_t stream)
{
  const float* x    = (const float*)d_in[0];
  const int*   ei   = (const int*)  d_in[1];
  const float* dts  = (const float*)d_in[2];
  const float* freq = (const float*)d_in[4];
  const float* phs  = (const float*)d_in[5];
  const float* tW1  = (const float*)d_in[6];
  const float* tb1  = (const float*)d_in[7];
  const float* tW2  = (const float*)d_in[8];
  const float* tb2  = (const float*)d_in[9];
  const float* pW   = (const float*)d_in[10];
  const float* pb   = (const float*)d_in[11];
  const float* sW1  = (const float*)d_in[12];
  const float* sb1  = (const float*)d_in[13];
  const float* sW2  = (const float*)d_in[14];
  const float* sb2  = (const float*)d_in[15];
  const float* bng  = (const float*)d_in[16];
  const float* bnb  = (const float*)d_in[17];
  const float* cW1  = (const float*)d_in[18];
  const float* cb1  = (const float*)d_in[19];
  const float* cg1  = (const float*)d_in[20];
  const float* cbb1 = (const float*)d_in[21];
  const float* cW2  = (const float*)d_in[22];
  const float* cb2  = (const float*)d_in[23];
  const float* cg2  = (const float*)d_in[24];
  const float* cbb2 = (const float*)d_in[25];
  const float* cW3  = (const float*)d_in[26];
  const float* cb3  = (const float*)d_in[27];
  float* out = (float*)d_out;

  const int N = in_sizes[0] / 17;
  const int E = in_sizes[1] / 2;
  const int B = out_size;

  // ---- workspace layout (byte offsets, union region for phase-local data) --
  char* base = (char*)d_ws;
  size_t off = 0;
  float* h    = (float*)(base + off); off += (size_t)N * 64 * 4;
  float* acc2 = (float*)(base + off); off += (size_t)N * 64 * 4;
  char*  uni  = base + off;           off += (size_t)N * 64 * 4;  // union
  float* bnsAll = (float*)(base + off); off += 8 * 64 * 4;        // 4 slot pairs
  unsigned short* W1t = (unsigned short*)(base + off); off += 2 * 64 * 128 * 2;
  unsigned short* W2t = (unsigned short*)(base + off); off += 2 * 64 * 64 * 2;
  unsigned short* cW1t = (unsigned short*)(base + off); off += 64 * 64 * 2;
  unsigned short* cW2t = (unsigned short*)(base + off); off += 32 * 64 * 2;
  int* cntI   = (int*)(base + off); off += (size_t)N * 4;
  int* cursor = (int*)(base + off); off += (size_t)N * 4;
  int* bsum   = (int*)(base + off); off += 512 * 4;
  int* bktBase = (int*)(base + off); off += 8 * 4;
  int* bktCur  = (int*)(base + off); off += 8 * 4;
  int* dstS   = (int*)(base + off); off += (size_t)E * 4;
  off = (off + 15) & ~(size_t)15;
  int2* srcdtS = (int2*)(base + off); off += (size_t)E * 8;
  size_t needed = off;
  if (ws_size < needed) return;  // fail visibly (output stays poisoned)

  // union members (phase1 | phase2 | classifier | bucket — lifetimes disjoint)
  float* acc1 = (float*)uni;                                     // N*17 f32
  unsigned short* xb   = (unsigned short*)(uni + (size_t)N * 17 * 4); // N*24
  unsigned short* W1t1 = xb + (size_t)N * 24;                    // 48*96
  unsigned short* W2t1 = W1t1 + 48 * 96;                         // 32*64
  unsigned short* P1 = (unsigned short*)uni;                     // N*64
  unsigned short* P2 = P1 + (size_t)N * 64;                      // N*64
  float* z1 = (float*)uni;                                       // B*64
  float* z2 = z1 + (size_t)B * 64;                               // B*32
  int*  bdst = (int*)uni;                                        // E (bucket dst)
  int2* bsd  = (int2*)(uni + (size_t)E * 4);                     // E (bucket src,dt)

  const int nwt = (E + 15) / 16;
  const int NB = (N + 255) / 256;
  if (NB > 512) return;

  // ---- init: cntI only (acc1/bnsAll zeroed inside prep_all) ----
  hipMemsetAsync(cntI, 0, (size_t)N * 4, stream);

  // ---- counting sort by dst: hist -> scan -> expand -> bucket -> scatter ----
  k_hist<<<(E + 255) / 256, 256, 0, stream>>>(ei, cntI, E);
  k_scan_block<<<NB, 256, 0, stream>>>(cntI, cursor, bsum, N);
  k_scan_bsum<<<1, 512, 0, stream>>>(bsum, NB);
  k_expand_add<<<NB, 256, 0, stream>>>(cursor, bsum, cntI, dstS,
                                       bktBase, bktCur, N);
  k_bucket<<<1024, 256, 0, stream>>>(ei, dts, bktCur, bdst, bsd, E, N);
  k_scatter2<<<1024, 256, 0, stream>>>(bktBase, bdst, bsd, cursor, srcdtS, E);
  prep_all<<<(N * 24 + 255) / 256, 256, 0, stream>>>(
      x, tW1, tW2, sW1, sW2, cW1, cW2, xb, W1t1, W2t1, W1t, W2t,
      cW1t, cW2t, acc1, bnsAll, N);

  // ---- phase 1 (768/(256,3) low-FETCH config, 2-deep prefetch) ----
  phase1_edge_mfma<<<768, 256, 0, stream>>>(
      xb, dstS, srcdtS, freq, phs, W1t1, tb1, W2t1, tb2, acc1, E, nwt);
  phase1_node<<<(N + 3) / 4, 256, 0, stream>>>(x, acc1, cntI, pW, pb, h, acc2, N);

  // ---- phase 2: L = 2 layers; BN(l) fused into the next consumer ----
  const int PB = (N + 63) / 64;
  // l = 0 (acc1 dead before this dispatch -> P1/P2 overlay is legal)
  prep_P<false><<<PB, 256, 0, stream>>>(
      h, W1t, sb1, nullptr, nullptr, nullptr, nullptr, 0.0f, P1, P2, N);
  phase2_edge<<<1280, 256, 0, stream>>>(
      P1, P2, dstS, srcdtS, W2t, sb2, acc2, E, nwt);
  node_update_bn<true><<<1024, 256, 0, stream>>>(h, acc2, cntI,
                                                 bnsAll + 0, bnsAll + 64, N);
  // l = 1 (prep_P applies BN of layer 0 and writes post-BN h back)
  prep_P<true><<<PB, 256, 0, stream>>>(
      h, W1t + (size_t)64 * 128, sb1 + 64, bnsAll + 0, bnsAll + 64,
      bng, bnb, 1.0f / (float)N, P1, P2, N);
  phase2_edge<<<1280, 256, 0, stream>>>(
      P1, P2, dstS, srcdtS, W2t + (size_t)64 * 64, sb2 + 64, acc2, E, nwt);
  node_update_bn<false><<<1024, 256, 0, stream>>>(h, acc2, cntI,
                                                  bnsAll + 128, bnsAll + 192, N);

  // ---- classifier: BN of layer 1 fused into clf_mfma<4> staging ----
  const int CB = (B + 63) / 64;
  clf_mfma<4><<<CB, 256, 0, stream>>>(
      h, cW1t, cb1, z1, bnsAll + 256, bnsAll + 320,
      bnsAll + 128, bnsAll + 192, bng + 64, bnb + 64, 1.0f / (float)N, B);
  clf_mfma<2><<<CB, 256, 0, stream>>>(
      z1, cW2t, cb2, z2, bnsAll + 384, bnsAll + 448,
      bnsAll + 256, bnsAll + 320, cg1, cbb1, 1.0f / (float)B, B);
  clf_final<<<(B + 255) / 256, 256, 0, stream>>>(
      z2, cW3, cb3, bnsAll + 384, bnsAll + 448, cg2, cbb2,
      1.0f / (float)B, out, B);
}

// Round 11
// 798.342 us; speedup vs baseline: 1.0082x; 1.0082x over previous
//
#include <hip/hip_runtime.h>
#include <hip/hip_bf16.h>

// ---------------------------------------------------------------------------
// THEGCNModel — R27 (revert to R22, the best-measured configuration, 796us):
//   * R23-R26 scatter saga: 8-pass scalar (85us) = 8-pass vectorized (85us)
//     > 1-pass (105us) ~ bucket 2-pass (net 0, +30ms profile outlier).
//     srcdtS partial-line write-amp is structural; ~85us is the floor
//     across 4 designs. Reverted to the 8-pass scalar (simplest = equal).
//   * Retained (proven): R19 edge bodies w/ 2-deep prefetch (idx t+2 /
//     payload t+1), phase1 768/(256,3) low-FETCH config, phase2
//     1280/(256,5), XCD dst-range tiling, full-wave cos, scalar segmented
//     walk, prep_all-fused memsets, node_update_bn<ZERO>.
//   * Falsified (do not retry): occupancy bumps on phase1 (L2 thrash,
//     FETCH 2x), per-wave tile pairing via by-ref lambdas (scratch spill),
//     node+prep fusion over the uni overlay (cross-block race).
// ---------------------------------------------------------------------------

typedef float  f32x4 __attribute__((ext_vector_type(4)));
typedef short  s16x8 __attribute__((ext_vector_type(8)));

__device__ __forceinline__ float tanh_factor(float u) {
  // 2*tanh(u)-1 == 1 - 4/(exp(2u)+1); rcp is 1-ulp approx (noise vs bf16)
  float e = __expf(2.0f * u);
  return fmaf(-4.0f, __builtin_amdgcn_rcpf(e + 1.0f), 1.0f);
}

__device__ __forceinline__ void atomic_add_f32(float* p, float v) {
  unsafeAtomicAdd(p, v);               // native global_atomic_add_f32
}

__device__ __forceinline__ unsigned short f2bf(float f) {
  __hip_bfloat16 b = __float2bfloat16(f);
  return *(unsigned short*)&b;
}
__device__ __forceinline__ float bf2f(unsigned short u) {
  unsigned int v = ((unsigned int)u) << 16;
  return *(float*)&v;
}

// ---------------------------------------------------------------------------
// Counting sort by dst: histogram -> scan -> expand(dstS) -> scatter(src,dts).
// ---------------------------------------------------------------------------
__global__ __launch_bounds__(256) void k_hist(
    const int* __restrict__ ei, int* __restrict__ cntI, int E)
{
  int e = blockIdx.x * 256 + threadIdx.x;
  if (e < E) atomicAdd(&cntI[__builtin_nontemporal_load(ei + E + e)], 1);
}

__global__ __launch_bounds__(256) void k_scan_block(
    const int* __restrict__ cntI, int* __restrict__ cursor,
    int* __restrict__ bsum, int N)
{
  __shared__ int s[256];
  const int t = threadIdx.x;
  int i = blockIdx.x * 256 + t;
  int v = (i < N) ? cntI[i] : 0;
  s[t] = v;
  for (int off = 1; off < 256; off <<= 1) {
    __syncthreads();
    int x = (t >= off) ? s[t - off] : 0;
    __syncthreads();
    s[t] += x;
  }
  __syncthreads();
  if (i < N) cursor[i] = s[t] - v;          // local exclusive
  if (t == 255) bsum[blockIdx.x] = s[255];
}

__global__ __launch_bounds__(512) void k_scan_bsum(int* __restrict__ bsum, int nb)
{
  __shared__ int s[512];
  const int t = threadIdx.x;
  int v = (t < nb) ? bsum[t] : 0;
  s[t] = v;
  for (int off = 1; off < 512; off <<= 1) {
    __syncthreads();
    int x = (t >= off) ? s[t - off] : 0;
    __syncthreads();
    s[t] += x;
  }
  __syncthreads();
  if (t < nb) bsum[t] = s[t] - v;           // exclusive
}

// fused: cursor += block offset (final rowPtr) AND expand dstS runs.
__global__ __launch_bounds__(256) void k_expand_add(
    int* __restrict__ cursor, const int* __restrict__ bsum,
    const int* __restrict__ cntI, int* __restrict__ dstS, int N)
{
  int n = blockIdx.x * 256 + threadIdx.x;
  if (n >= N) return;
  int cur = cursor[n] + bsum[blockIdx.x];
  cursor[n] = cur;
  int c = cntI[n];
  for (int i = 0; i < c; i++) dstS[cur + i] = n;
}

// XCD-partitioned scatter: group g = blockIdx&7 handles dst in [N*g/8,N*(g+1)/8)
// -> its srcdtS segment (~1.6MB) fits one XCD L2, lines fill fully.
__global__ __launch_bounds__(256) void k_scatter_x(
    const int* __restrict__ ei, const float* __restrict__ dts,
    int* __restrict__ cursor, int2* __restrict__ srcdtS, int E, int N)
{
  const int g  = blockIdx.x & 7;           // XCD proxy (round-robin heuristic)
  const int bi = blockIdx.x >> 3;
  const int nb = gridDim.x >> 3;
  const int lo = (int)(((long long)N * g) >> 3);
  const int hi = (int)(((long long)N * (g + 1)) >> 3);
  for (int e = bi * 256 + threadIdx.x; e < E; e += nb * 256) {
    int d = __builtin_nontemporal_load(ei + E + e);
    if (d >= lo && d < hi) {
      int s = __builtin_nontemporal_load(ei + e);
      float dt = __builtin_nontemporal_load(dts + e);
      int pos = atomicAdd(&cursor[d], 1);
      srcdtS[pos] = make_int2(s, __float_as_int(dt));
    }
  }
}

// ---------------------------------------------------------------------------
// prep_all: xb = bf16(x) padded to 24 cols; phase-1 weights W1t1/W2t1; phase-2
// weights W1t/W2t; classifier weights cW1t/cW2t; zeroes acc1 (N*17 f32) and
// bnsAll (512 f32) — replaces two memset dispatches (stream-ordered before
// any consumer).
// ---------------------------------------------------------------------------
__global__ __launch_bounds__(256) void prep_all(
    const float* __restrict__ x, const float* __restrict__ tW1,
    const float* __restrict__ tW2, const float* __restrict__ sW1,
    const float* __restrict__ sW2, const float* __restrict__ cW1,
    const float* __restrict__ cW2, unsigned short* __restrict__ xb,
    unsigned short* __restrict__ W1t1, unsigned short* __restrict__ W2t1,
    unsigned short* __restrict__ W1t, unsigned short* __restrict__ W2t,
    unsigned short* __restrict__ cW1t, unsigned short* __restrict__ cW2t,
    float* __restrict__ acc1, float* __restrict__ bnsAll, int N)
{
  int i = blockIdx.x * 256 + threadIdx.x;
  int totalX = N * 24;
  for (int idx = i; idx < totalX; idx += gridDim.x * 256) {
    int n = idx / 24, c = idx - n * 24;
    xb[idx] = (c < 17) ? f2bf(x[n * 17 + c]) : (unsigned short)0;
  }
  // zero acc1 (N*17) + bnsAll (512)
  for (int idx = i; idx < N * 17; idx += gridDim.x * 256) acc1[idx] = 0.0f;
  if (i < 512) bnsAll[i] = 0.0f;
  if (i < 48 * 96) {
    int n = i / 96, k = i - n * 96;
    int src = (k < 17) ? k : (k >= 24 && k < 41) ? (k - 24 + 17)
            : (k >= 48 && k < 80) ? (k - 48 + 34) : -1;
    W1t1[i] = (n < 33 && src >= 0) ? f2bf(tW1[src * 33 + n]) : (unsigned short)0;
  }
  if (i < 32 * 64) {
    int n = i / 64, k = i - n * 64;
    W2t1[i] = (n < 17 && k < 33) ? f2bf(tW2[k * 17 + n]) : (unsigned short)0;
  }
  if (i < 2 * 64 * 128) {
    int l = i >> 13; int r = i & 8191; int n = r >> 7; int k = r & 127;
    W1t[i] = f2bf(sW1[((size_t)l * 128 + k) * 64 + n]);
  }
  if (i < 2 * 64 * 64) {
    int l = i >> 12; int r = i & 4095; int n = r >> 6; int k = r & 63;
    W2t[i] = f2bf(sW2[((size_t)l * 64 + k) * 64 + n]);
  }
  if (i < 64 * 64) {
    int c = i >> 6, k = i & 63;
    cW1t[i] = f2bf(cW1[k * 64 + c]);
  }
  if (i < 32 * 64) {
    int c = i >> 6, k = i & 63;
    cW2t[i] = f2bf(cW2[k * 32 + c]);
  }
}

// ---------------------------------------------------------------------------
// Phase 1 edge kernel (MFMA, barrier-free wave-private 16-edge tiles).
// R22: R19 body (2-deep prefetch: idx(t+2)/payload(t+1)) at the low-FETCH
// config 768/(256,3).
// ---------------------------------------------------------------------------
__global__ __launch_bounds__(256, 3) void phase1_edge_mfma(
    const unsigned short* __restrict__ xb, const int* __restrict__ dstS,
    const int2* __restrict__ srcdtS, const float* __restrict__ freq,
    const float* __restrict__ phs,
    const unsigned short* __restrict__ W1t1, const float* __restrict__ b1,
    const unsigned short* __restrict__ W2t1, const float* __restrict__ b2,
    float* __restrict__ accum, int E, int nwt)
{
  __shared__ unsigned short sA[64][104];
  __shared__ unsigned short sHid[64][72];
  __shared__ float sRed[64][20];
  __shared__ int   sDst[64];

  const int t = threadIdx.x;
  const int wv = t >> 6, lane = t & 63, l16 = lane & 15, quad = lane >> 4;
  const int r0 = wv * 16;
  const int e_loc = lane >> 2, q = lane & 3;
  const int rr = r0 + e_loc;

  s16x8 w1f[3][3], w2f[2][2];
  float bias1[3], bias2[2];
#pragma unroll
  for (int cb = 0; cb < 3; cb++) {
    int n = cb * 16 + l16;
#pragma unroll
    for (int kb = 0; kb < 3; kb++)
      w1f[cb][kb] = *(const s16x8*)&W1t1[n * 96 + kb * 32 + quad * 8];
    bias1[cb] = (n < 33) ? b1[n] : 0.0f;
  }
#pragma unroll
  for (int cb = 0; cb < 2; cb++) {
    int n = cb * 16 + l16;
#pragma unroll
    for (int kb = 0; kb < 2; kb++)
      w2f[cb][kb] = *(const s16x8*)&W2t1[n * 64 + kb * 32 + quad * 8];
    bias2[cb] = (n < 17) ? b2[n] : 0.0f;
  }

  // loop-invariant rel coefficients: this lane covers k = q*8 .. q*8+7
  float frq[8], phv[8];
#pragma unroll
  for (int j = 0; j < 8; j++) {
    frq[j] = freq[q * 8 + j];
    phv[j] = phs[q * 8 + j];
  }

  // zero own-wave pad columns once
  for (int i = lane; i < 16 * 28; i += 64) {
    int rrz = r0 + i / 28, c = i % 28;
    int col = (c < 6) ? 18 + c : (c < 12) ? 42 + (c - 6) : 80 + (c - 12);
    sA[rrz][col] = 0;
  }
  for (int i = lane; i < 256; i += 64)
    sHid[r0 + (i >> 4)][48 + (i & 15)] = 0;

  // XCD dst-range tiling: group g = blockIdx&7 owns [nwt*g/8, nwt*(g+1)/8).
  const int g8   = blockIdx.x & 7;
  const int tLo  = (int)(((long long)nwt * g8) >> 3);
  const int tHi  = (int)(((long long)nwt * (g8 + 1)) >> 3);
  const int wLoc = (blockIdx.x >> 3) * 4 + wv;
  const int nwLoc = (gridDim.x >> 3) * 4;

  // -- 2-deep pipeline: idx for tile t+1 (idxN/dtN), payload for tile t --
  int idxN = 0; float dtN = 0.0f;
  int ndP = 0; uint4 xa0, xa1; unsigned int xa2 = 0; float dtP = 0.0f;
  auto issue_idx = [&](int tt) {
    int er = (tt << 4) + e_loc; if (er >= E) er = E - 1;
    int2 sd = srcdtS[er];
    idxN = q ? sd.x : dstS[er];
    dtN  = __int_as_float(sd.y);
  };
  auto issue_payload = [&]() {           // consumes idxN/dtN already in regs
    ndP = idxN; dtP = dtN;
    if (q < 2) {
      const unsigned short* src = &xb[(size_t)ndP * 24];
      xa0 = *(const uint4*)&src[0];
      xa1 = *(const uint4*)&src[8];
      xa2 = *(const unsigned int*)&src[16];
    }
  };
  {
    int t0 = tLo + wLoc; if (t0 >= nwt) t0 = nwt - 1;
    issue_idx(t0);
    issue_payload();
    int t1 = t0 + nwLoc; if (t1 >= tHi) t1 = t0;
    issue_idx(t1);
  }

  for (int tile = tLo + wLoc; tile < tHi; tile += nwLoc) {
    const int eb = tile << 4;

    // stage pipelined regs -> LDS (own rows only; same-wave ordering)
    if (q < 2) {
      if (!q) sDst[rr] = ndP;
      const int base = q ? 24 : 0;
      *(uint4*)&sA[rr][base]     = xa0;
      *(uint4*)&sA[rr][base + 8] = xa1;
      *(unsigned int*)&sA[rr][base + 16] = xa2;
    }
    // all 64 lanes: 8 rel values each (k = q*8 + j) — no divergent half-wave
    {
      unsigned short tmp[8] __attribute__((aligned(16)));
#pragma unroll
      for (int j = 0; j < 8; j++)
        tmp[j] = f2bf(__cosf(fmaf(dtP, frq[j], phv[j])));
      *(uint4*)&sA[rr][48 + q * 8] = *(const uint4*)&tmp[0];
    }

    // payload gather for t+1 (index already resident — no dependent wait);
    // then index fetch for t+2. Both hide under pass1/pass2/tanh/walk.
    issue_payload();
    { int nt = tile + 2 * nwLoc; issue_idx(nt < tHi ? nt : tile); }

    // pass1: hid = relu(A @ W1 + b1)   (own row r0+l16)
    f32x4 a1[3];
#pragma unroll
    for (int cb = 0; cb < 3; cb++)
      a1[cb] = (f32x4){bias1[cb], bias1[cb], bias1[cb], bias1[cb]};
#pragma unroll
    for (int kb = 0; kb < 3; kb++) {
      s16x8 aF = *(const s16x8*)&sA[r0 + l16][kb * 32 + quad * 8];
#pragma unroll
      for (int cb = 0; cb < 3; cb++)
        a1[cb] = __builtin_amdgcn_mfma_f32_16x16x32_bf16(aF, w1f[cb][kb], a1[cb], 0, 0, 0);
    }
#pragma unroll
    for (int cb = 0; cb < 3; cb++)
#pragma unroll
      for (int reg = 0; reg < 4; reg++)
        sHid[r0 + quad * 4 + reg][cb * 16 + l16] = f2bf(fmaxf(a1[cb][reg], 0.0f));

    // pass2: u = hid @ W2 + b2
    f32x4 a2[2];
#pragma unroll
    for (int cb = 0; cb < 2; cb++)
      a2[cb] = (f32x4){bias2[cb], bias2[cb], bias2[cb], bias2[cb]};
#pragma unroll
    for (int kb = 0; kb < 2; kb++) {
      s16x8 aF = *(const s16x8*)&sHid[r0 + l16][kb * 32 + quad * 8];
#pragma unroll
      for (int cb = 0; cb < 2; cb++)
        a2[cb] = __builtin_amdgcn_mfma_f32_16x16x32_bf16(aF, w2f[cb][kb], a2[cb], 0, 0, 0);
    }

    // f -> sRed (own rows)
#pragma unroll
    for (int reg = 0; reg < 4; reg++) {
      int row = r0 + quad * 4 + reg;
      bool ok = (eb + quad * 4 + reg < E);
      sRed[row][l16] = ok ? tanh_factor(a2[0][reg]) : 0.0f;
      if (l16 == 0) sRed[row][16] = ok ? tanh_factor(a2[1][reg]) : 0.0f;
    }

    // wave-local segmented walk: lanes 0..16, col = lane, own 16 rows.
    if (lane < 17) {
      int col = lane;
      float run = 0.0f;
      int cur = __builtin_amdgcn_readfirstlane(sDst[r0]);
#pragma unroll
      for (int k = 0; k < 16; k++) {
        int d = __builtin_amdgcn_readfirstlane(sDst[r0 + k]);
        float v = sRed[r0 + k][col];
        if (d != cur) {
          atomic_add_f32(&accum[(size_t)cur * 17 + col], run);
          run = 0.0f; cur = d;
        }
        run += v;
      }
      atomic_add_f32(&accum[(size_t)cur * 17 + col], run);
    }
  }
}

// ---------------------------------------------------------------------------
// Phase 1 node kernel: h[n] = (x[n] * (1 + acc/max(cnt,1))) @ projW + projb.
// Also zeroes acc2 (replaces a 25.6MB memset dispatch).
// ---------------------------------------------------------------------------
__global__ __launch_bounds__(256) void phase1_node(
    const float* __restrict__ x, const float* __restrict__ acc1,
    const int* __restrict__ cntI, const float* __restrict__ Wp,
    const float* __restrict__ bp, float* __restrict__ h,
    float* __restrict__ acc2, int N)
{
  __shared__ float s0[4][20];
  const int t = threadIdx.x;
  const int nb = blockIdx.x << 2;
  if (t < 68) {
    int nl = t / 17, c = t % 17;
    int n = nb + nl;
    float v = 0.0f;
    if (n < N) {
      float cnt = fmaxf((float)cntI[n], 1.0f);
      v = x[n * 17 + c] * (1.0f + acc1[n * 17 + c] / cnt);
    }
    s0[nl][c] = v;
  }
  __syncthreads();
  int nl = t >> 6, j = t & 63;
  int n = nb + nl;
  if (n < N) {
    float acc = bp[j];
#pragma unroll
    for (int c = 0; c < 17; c++) acc = fmaf(s0[nl][c], Wp[c * 64 + j], acc);
    h[n * 64 + j] = acc;
    acc2[n * 64 + j] = 0.0f;
  }
}

// ---------------------------------------------------------------------------
// prep_P<DO_BN>: P1[n] = h'[n]@W1a + b1, P2[n] = h'[n]@W1b where
// h' = DO_BN ? relu(BN(h)) : h. DO_BN also writes h' back.
// ---------------------------------------------------------------------------
template <bool DO_BN>
__global__ void prep_P(
    float* __restrict__ h, const unsigned short* __restrict__ W1t,
    const float* __restrict__ b1,
    const float* __restrict__ bns, const float* __restrict__ bnq,
    const float* __restrict__ gam, const float* __restrict__ bet, float invR,
    unsigned short* __restrict__ P1, unsigned short* __restrict__ P2, int N)
{
  __shared__ unsigned short sH[64][72];
  __shared__ float sM[64], sS[64], sB[64];
  const int t = threadIdx.x;
  const int wv = t >> 6, lane = t & 63, l16 = lane & 15, quad = lane >> 4;
  const int nb = blockIdx.x << 6;

  if (DO_BN) {
    if (t < 64) {
      float m = bns[t] * invR;
      float var = bnq[t] * invR - m * m;
      sM[t] = m;
      sS[t] = gam[t] * rsqrtf(var + 1e-5f);
      sB[t] = bet[t];
    }
    __syncthreads();
  }

#pragma unroll
  for (int i = 0; i < 4; i++) {
    int g = t + i * 256;
    int r = g >> 4, c4 = (g & 15) << 2;
    int n0 = nb + r;
    bool valid = (n0 < N);
    int n = valid ? n0 : N - 1;
    float4 v = *(const float4*)&h[(size_t)n * 64 + c4];
    if (DO_BN) {
      v.x = fmaxf(fmaf(v.x - sM[c4 + 0], sS[c4 + 0], sB[c4 + 0]), 0.0f);
      v.y = fmaxf(fmaf(v.y - sM[c4 + 1], sS[c4 + 1], sB[c4 + 1]), 0.0f);
      v.z = fmaxf(fmaf(v.z - sM[c4 + 2], sS[c4 + 2], sB[c4 + 2]), 0.0f);
      v.w = fmaxf(fmaf(v.w - sM[c4 + 3], sS[c4 + 3], sB[c4 + 3]), 0.0f);
      if (valid) *(float4*)&h[(size_t)n0 * 64 + c4] = v;
    }
    ushort4 o = { f2bf(v.x), f2bf(v.y), f2bf(v.z), f2bf(v.w) };
    *(ushort4*)&sH[r][c4] = o;
  }
  __syncthreads();

  const int n = nb + wv * 16 + l16;
#pragma unroll
  for (int half = 0; half < 2; half++) {
    f32x4 acc[4];
#pragma unroll
    for (int cb = 0; cb < 4; cb++) {
      if (half == 0) {
        float4 bv = *(const float4*)&b1[cb * 16 + quad * 4];
        acc[cb] = (f32x4){bv.x, bv.y, bv.z, bv.w};
      } else {
        acc[cb] = (f32x4){0.0f, 0.0f, 0.0f, 0.0f};
      }
    }
#pragma unroll
    for (int kb = 0; kb < 2; kb++) {
      s16x8 bF = *(const s16x8*)&sH[wv * 16 + l16][kb * 32 + quad * 8];
#pragma unroll
      for (int cb = 0; cb < 4; cb++) {
        s16x8 aF = *(const s16x8*)&W1t[(cb * 16 + l16) * 128 + half * 64 + kb * 32 + quad * 8];
        acc[cb] = __builtin_amdgcn_mfma_f32_16x16x32_bf16(aF, bF, acc[cb], 0, 0, 0);
      }
    }
    if (n < N) {
      unsigned short* P = half ? P2 : P1;
#pragma unroll
      for (int cb = 0; cb < 4; cb++) {
        ushort4 o = { f2bf(acc[cb][0]), f2bf(acc[cb][1]),
                      f2bf(acc[cb][2]), f2bf(acc[cb][3]) };
        *(ushort4*)&P[(size_t)n * 64 + cb * 16 + quad * 4] = o;
      }
    }
  }
}

// ---------------------------------------------------------------------------
// Phase 2 edge kernel — barrier-free wave-private 16-edge tiles.
// R19 exact: bounds(256,5), grid 1280, 2-deep prefetch idx(t+2)/payload(t+1).
// ---------------------------------------------------------------------------
__global__ __launch_bounds__(256, 5) void phase2_edge(
    const unsigned short* __restrict__ P1, const unsigned short* __restrict__ P2,
    const int* __restrict__ dstS, const int2* __restrict__ srcdtS,
    const unsigned short* __restrict__ W2t, const float* __restrict__ b2,
    float* __restrict__ accum, int E, int nwt)
{
  __shared__ unsigned short sA[64][136];   // [edge][0:64]=P1[dst], [64:128]=P2[src]
  __shared__ int sDst[64];
  float* sRedF = (float*)&sA[0][0];        // aliased 64x68 f32 (same stride 272B)

  const int t = threadIdx.x;
  const int wv = t >> 6, lane = t & 63, l16 = lane & 15, quad = lane >> 4;
  const int r0 = wv * 16;

  s16x8 w2f[4][2];
  f32x4 bias2v[4];
#pragma unroll
  for (int cb = 0; cb < 4; cb++) {
#pragma unroll
    for (int kb = 0; kb < 2; kb++)
      w2f[cb][kb] = *(const s16x8*)&W2t[(cb * 16 + l16) * 64 + kb * 32 + quad * 8];
    float4 bv = *(const float4*)&b2[cb * 16 + quad * 4];
    bias2v[cb] = (f32x4){bv.x, bv.y, bv.z, bv.w};
  }

  const int eRow = r0 + l16;

  const int e_loc = lane >> 2, q = lane & 3;
  const int rr = r0 + e_loc;
  const unsigned short* const Pb = (q < 2) ? P1 : P2;
  const int cb0 = q * 32;
  const size_t sub = (size_t)((q & 1) * 32);

  // XCD dst-range tiling: group g = blockIdx&7 owns [nwt*g/8, nwt*(g+1)/8).
  const int g8   = blockIdx.x & 7;
  const int tLo  = (int)(((long long)nwt * g8) >> 3);
  const int tHi  = (int)(((long long)nwt * (g8 + 1)) >> 3);
  const int wLoc = (blockIdx.x >> 3) * 4 + wv;
  const int nwLoc = (gridDim.x >> 3) * 4;

  // -- 2-deep pipeline: idx for tile t+1, payload (64B row-quarter) for t --
  int idxN = 0;
  int ndP = 0; uint4 pA, pB, pC, pD;
  auto issue_idx = [&](int tt) {
    int er = (tt << 4) + e_loc; if (er >= E) er = E - 1;
    idxN = (q < 2) ? dstS[er] : srcdtS[er].x;
  };
  auto issue_payload = [&]() {           // consumes idxN already in regs
    ndP = idxN;
    const unsigned short* src = Pb + (size_t)ndP * 64 + sub;
    pA = *(const uint4*)&src[0];
    pB = *(const uint4*)&src[8];
    pC = *(const uint4*)&src[16];
    pD = *(const uint4*)&src[24];
  };
  {
    int t0 = tLo + wLoc; if (t0 >= nwt) t0 = nwt - 1;
    issue_idx(t0);
    issue_payload();
    int t1 = t0 + nwLoc; if (t1 >= tHi) t1 = t0;
    issue_idx(t1);
  }

  for (int tile = tLo + wLoc; tile < tHi; tile += nwLoc) {
    const int eb = tile << 4;

    // stage pipelined regs -> LDS (own rows only; same-wave ordering)
    if (q == 0) sDst[rr] = ndP;
    *(uint4*)&sA[rr][cb0]      = pA;
    *(uint4*)&sA[rr][cb0 + 8]  = pB;
    *(uint4*)&sA[rr][cb0 + 16] = pC;
    *(uint4*)&sA[rr][cb0 + 24] = pD;

    // payload gather for t+1 (index already resident), then idx for t+2.
    issue_payload();
    { int nt = tile + 2 * nwLoc; issue_idx(nt < tHi ? nt : tile); }

    // hidden B-frags: relu(P1+P2), packed bf16 (own row)
    s16x8 hidf[2];
#pragma unroll
    for (int kb = 0; kb < 2; kb++) {
      s16x8 x1 = *(const s16x8*)&sA[eRow][kb * 32 + quad * 8];
      s16x8 x2 = *(const s16x8*)&sA[eRow][64 + kb * 32 + quad * 8];
      s16x8 hf;
#pragma unroll
      for (int j = 0; j < 8; j++) {
        float a = bf2f((unsigned short)x1[j]);
        float b = bf2f((unsigned short)x2[j]);
        hf[j] = (short)f2bf(fmaxf(a + b, 0.0f));
      }
      hidf[kb] = hf;
    }

    // u^T[n2][edge] = W2t @ hidden^T + b2
    f32x4 acc[4];
#pragma unroll
    for (int cb = 0; cb < 4; cb++) acc[cb] = bias2v[cb];
#pragma unroll
    for (int kb = 0; kb < 2; kb++)
#pragma unroll
      for (int cb = 0; cb < 4; cb++)
        acc[cb] = __builtin_amdgcn_mfma_f32_16x16x32_bf16(w2f[cb][kb], hidf[kb], acc[cb], 0, 0, 0);

    // f = 2*tanh(u)-1 -> sRedF (own rows; same-wave ordering)
    bool ok = (eb + l16 < E);
#pragma unroll
    for (int cb = 0; cb < 4; cb++) {
      f32x4 f;
#pragma unroll
      for (int reg = 0; reg < 4; reg++)
        f[reg] = ok ? tanh_factor(acc[cb][reg]) : 0.0f;
      *(f32x4*)&sRedF[eRow * 68 + cb * 16 + quad * 4] = f;
    }

    // wave-local segmented walk: lane = col, own 16 rows.
    {
      float run = 0.0f;
      int cur = __builtin_amdgcn_readfirstlane(sDst[r0]);
#pragma unroll
      for (int k = 0; k < 16; k++) {
        int d = __builtin_amdgcn_readfirstlane(sDst[r0 + k]);
        float v = sRedF[(r0 + k) * 68 + lane];
        if (d != cur) {                       // scalar branch
          atomic_add_f32(&accum[(size_t)cur * 64 + lane], run);
          run = 0.0f; cur = d;
        }
        run += v;
      }
      atomic_add_f32(&accum[(size_t)cur * 64 + lane], run);
    }
  }
}

// ---------------------------------------------------------------------------
// Node update + BN statistics. ZERO: re-zero accum for the next layer
// (skipped on the last layer — saves a 25.6MB write).
// ---------------------------------------------------------------------------
template <bool ZERO>
__global__ __launch_bounds__(256) void node_update_bn(
    float* __restrict__ h, float* __restrict__ accum,
    const int* __restrict__ cntI, float* __restrict__ bns,
    float* __restrict__ bnq, int N)
{
  const int t = threadIdx.x;
  float ls = 0.0f, lq = 0.0f;
  int total = N * 64;
  for (int idx = blockIdx.x * 256 + t; idx < total; idx += gridDim.x * 256) {
    int n = idx >> 6;
    float cnt = fmaxf((float)cntI[n], 1.0f);
    float v = h[idx] * (1.0f + accum[idx] / cnt);
    if (ZERO) accum[idx] = 0.0f;       // ready for next layer's scatter
    h[idx] = v;
    ls += v; lq += v * v;
  }
  __shared__ float ss[256], sq[256];
  ss[t] = ls; sq[t] = lq;
  __syncthreads();
  if (t < 64) {
    float s = ss[t] + ss[t + 64] + ss[t + 128] + ss[t + 192];
    float q = sq[t] + sq[t + 64] + sq[t + 128] + sq[t + 192];
    atomic_add_f32(&bns[t], s);
    atomic_add_f32(&bnq[t], q);
  }
}

// ---------------------------------------------------------------------------
// Classifier MFMA with input-BN fused at staging.
// ---------------------------------------------------------------------------
template <int NCB>
__global__ __launch_bounds__(256) void clf_mfma(
    const float* __restrict__ in, const unsigned short* __restrict__ Wt,
    const float* __restrict__ bias, float* __restrict__ z,
    float* __restrict__ bns, float* __restrict__ bnq,
    const float* __restrict__ ibns, const float* __restrict__ ibnq,
    const float* __restrict__ igam, const float* __restrict__ ibet,
    float iinvR, int rows)
{
  __shared__ unsigned short sIn[64][72];
  __shared__ float sM[64], sS[64], sB[64];
  const int t = threadIdx.x;
  const int wv = t >> 6, lane = t & 63, l16 = lane & 15, quad = lane >> 4;
  const int nb = blockIdx.x << 6;

  if (t < 64) {
    float m = ibns[t] * iinvR;
    float var = ibnq[t] * iinvR - m * m;
    sM[t] = m;
    sS[t] = igam[t] * rsqrtf(var + 1e-5f);
    sB[t] = ibet[t];
  }

  s16x8 wf[NCB][2];
  f32x4 bv[NCB];
#pragma unroll
  for (int cb = 0; cb < NCB; cb++) {
#pragma unroll
    for (int kb = 0; kb < 2; kb++)
      wf[cb][kb] = *(const s16x8*)&Wt[(cb * 16 + l16) * 64 + kb * 32 + quad * 8];
    float4 b4 = *(const float4*)&bias[cb * 16 + quad * 4];
    bv[cb] = (f32x4){b4.x, b4.y, b4.z, b4.w};
  }
  __syncthreads();   // sM/sS/sB visible

#pragma unroll
  for (int i = 0; i < 4; i++) {
    int g = t + i * 256;
    int r = g >> 4, c4 = (g & 15) << 2;
    int n = nb + r; if (n >= rows) n = rows - 1;
    float4 v = *(const float4*)&in[(size_t)n * 64 + c4];
    v.x = fmaxf(fmaf(v.x - sM[c4 + 0], sS[c4 + 0], sB[c4 + 0]), 0.0f);
    v.y = fmaxf(fmaf(v.y - sM[c4 + 1], sS[c4 + 1], sB[c4 + 1]), 0.0f);
    v.z = fmaxf(fmaf(v.z - sM[c4 + 2], sS[c4 + 2], sB[c4 + 2]), 0.0f);
    v.w = fmaxf(fmaf(v.w - sM[c4 + 3], sS[c4 + 3], sB[c4 + 3]), 0.0f);
    ushort4 o = { f2bf(v.x), f2bf(v.y), f2bf(v.z), f2bf(v.w) };
    *(ushort4*)&sIn[r][c4] = o;
  }
  __syncthreads();

  const int n = nb + wv * 16 + l16;
  const bool ok = (n < rows);
  f32x4 acc[NCB];
#pragma unroll
  for (int cb = 0; cb < NCB; cb++) acc[cb] = bv[cb];
#pragma unroll
  for (int kb = 0; kb < 2; kb++) {
    s16x8 bF = *(const s16x8*)&sIn[wv * 16 + l16][kb * 32 + quad * 8];
#pragma unroll
    for (int cb = 0; cb < NCB; cb++)
      acc[cb] = __builtin_amdgcn_mfma_f32_16x16x32_bf16(wf[cb][kb], bF, acc[cb], 0, 0, 0);
  }

  // store z (f32) + per-col stats reduced over the wave's 16 rows
#pragma unroll
  for (int cb = 0; cb < NCB; cb++) {
    if (ok)
      *(float4*)&z[(size_t)n * (NCB * 16) + cb * 16 + quad * 4] =
          make_float4(acc[cb][0], acc[cb][1], acc[cb][2], acc[cb][3]);
    f32x4 s, q;
#pragma unroll
    for (int reg = 0; reg < 4; reg++) {
      float v = ok ? acc[cb][reg] : 0.0f;
      s[reg] = v; q[reg] = v * v;
    }
#pragma unroll
    for (int m = 1; m < 16; m <<= 1) {
#pragma unroll
      for (int reg = 0; reg < 4; reg++) {
        s[reg] += __shfl_xor(s[reg], m);
        q[reg] += __shfl_xor(q[reg], m);
      }
    }
    if (l16 == 0) {
#pragma unroll
      for (int reg = 0; reg < 4; reg++) {
        int col = cb * 16 + quad * 4 + reg;
        atomic_add_f32(&bns[col], s[reg]);
        atomic_add_f32(&bnq[col], q[reg]);
      }
    }
  }
}

// clf_final with fused input BN (slot stats over 32 cols).
__global__ __launch_bounds__(256) void clf_final(
    const float* __restrict__ z2, const float* __restrict__ W3,
    const float* __restrict__ b3,
    const float* __restrict__ ibns, const float* __restrict__ ibnq,
    const float* __restrict__ igam, const float* __restrict__ ibet,
    float iinvR, float* __restrict__ out, int rows)
{
  __shared__ float sM[32], sS[32], sB[32];
  const int t = threadIdx.x;
  if (t < 32) {
    float m = ibns[t] * iinvR;
    float var = ibnq[t] * iinvR - m * m;
    sM[t] = m;
    sS[t] = igam[t] * rsqrtf(var + 1e-5f);
    sB[t] = ibet[t];
  }
  __syncthreads();
  int n = blockIdx.x * 256 + t;
  if (n >= rows) return;
  float acc = b3[0];
#pragma unroll
  for (int k = 0; k < 32; k++) {
    float v = fmaxf(fmaf(z2[n * 32 + k] - sM[k], sS[k], sB[k]), 0.0f);
    acc = fmaf(v, W3[k], acc);
  }
  out[n] = acc;
}

// ---------------------------------------------------------------------------
extern "C" void kernel_launch(void* const* d_in, const int* in_sizes, int n_in,
                              void* d_out, int out_size, void* d_ws, size_t ws_size,
                              hipStream_t stream)
{
  const float* x    = (const float*)d_in[0];
  const int*   ei   = (const int*)  d_in[1];
  const float* dts  = (const float*)d_in[2];
  const float* freq = (const float*)d_in[4];
  const float* phs  = (const float*)d_in[5];
  const float* tW1  = (const float*)d_in[6];
  const float* tb1  = (const float*)d_in[7];
  const float* tW2  = (const float*)d_in[8];
  const float* tb2  = (const float*)d_in[9];
  const float* pW   = (const float*)d_in[10];
  const float* pb   = (const float*)d_in[11];
  const float* sW1  = (const float*)d_in[12];
  const float* sb1  = (const float*)d_in[13];
  const float* sW2  = (const float*)d_in[14];
  const float* sb2  = (const float*)d_in[15];
  const float* bng  = (const float*)d_in[16];
  const float* bnb  = (const float*)d_in[17];
  const float* cW1  = (const float*)d_in[18];
  const float* cb1  = (const float*)d_in[19];
  const float* cg1  = (const float*)d_in[20];
  const float* cbb1 = (const float*)d_in[21];
  const float* cW2  = (const float*)d_in[22];
  const float* cb2  = (const float*)d_in[23];
  const float* cg2  = (const float*)d_in[24];
  const float* cbb2 = (const float*)d_in[25];
  const float* cW3  = (const float*)d_in[26];
  const float* cb3  = (const float*)d_in[27];
  float* out = (float*)d_out;

  const int N = in_sizes[0] / 17;
  const int E = in_sizes[1] / 2;
  const int B = out_size;

  // ---- workspace layout (byte offsets, union region for phase-local data) --
  char* base = (char*)d_ws;
  size_t off = 0;
  float* h    = (float*)(base + off); off += (size_t)N * 64 * 4;
  float* acc2 = (float*)(base + off); off += (size_t)N * 64 * 4;
  char*  uni  = base + off;           off += (size_t)N * 64 * 4;  // union
  float* bnsAll = (float*)(base + off); off += 8 * 64 * 4;        // 4 slot pairs
  unsigned short* W1t = (unsigned short*)(base + off); off += 2 * 64 * 128 * 2;
  unsigned short* W2t = (unsigned short*)(base + off); off += 2 * 64 * 64 * 2;
  unsigned short* cW1t = (unsigned short*)(base + off); off += 64 * 64 * 2;
  unsigned short* cW2t = (unsigned short*)(base + off); off += 32 * 64 * 2;
  int* cntI   = (int*)(base + off); off += (size_t)N * 4;
  int* cursor = (int*)(base + off); off += (size_t)N * 4;
  int* bsum   = (int*)(base + off); off += 512 * 4;
  int* dstS   = (int*)(base + off); off += (size_t)E * 4;
  off = (off + 15) & ~(size_t)15;
  int2* srcdtS = (int2*)(base + off); off += (size_t)E * 8;
  size_t needed = off;
  if (ws_size < needed) return;  // fail visibly (output stays poisoned)

  // union members (phase1 | phase2 | classifier — lifetimes disjoint)
  float* acc1 = (float*)uni;                                     // N*17 f32
  unsigned short* xb   = (unsigned short*)(uni + (size_t)N * 17 * 4); // N*24
  unsigned short* W1t1 = xb + (size_t)N * 24;                    // 48*96
  unsigned short* W2t1 = W1t1 + 48 * 96;                         // 32*64
  unsigned short* P1 = (unsigned short*)uni;                     // N*64
  unsigned short* P2 = P1 + (size_t)N * 64;                      // N*64
  float* z1 = (float*)uni;                                       // B*64
  float* z2 = z1 + (size_t)B * 64;                               // B*32

  const int nwt = (E + 15) / 16;
  const int NB = (N + 255) / 256;
  if (NB > 512) return;

  // ---- init: cntI only (acc1/bnsAll zeroed inside prep_all) ----
  hipMemsetAsync(cntI, 0, (size_t)N * 4, stream);

  // ---- counting sort by dst (yields counts + dstS) + weight/x prep ----
  k_hist<<<(E + 255) / 256, 256, 0, stream>>>(ei, cntI, E);
  k_scan_block<<<NB, 256, 0, stream>>>(cntI, cursor, bsum, N);
  k_scan_bsum<<<1, 512, 0, stream>>>(bsum, NB);
  k_expand_add<<<NB, 256, 0, stream>>>(cursor, bsum, cntI, dstS, N);
  k_scatter_x<<<1024, 256, 0, stream>>>(ei, dts, cursor, srcdtS, E, N);
  prep_all<<<(N * 24 + 255) / 256, 256, 0, stream>>>(
      x, tW1, tW2, sW1, sW2, cW1, cW2, xb, W1t1, W2t1, W1t, W2t,
      cW1t, cW2t, acc1, bnsAll, N);

  // ---- phase 1 (768/(256,3) low-FETCH config, 2-deep prefetch) ----
  phase1_edge_mfma<<<768, 256, 0, stream>>>(
      xb, dstS, srcdtS, freq, phs, W1t1, tb1, W2t1, tb2, acc1, E, nwt);
  phase1_node<<<(N + 3) / 4, 256, 0, stream>>>(x, acc1, cntI, pW, pb, h, acc2, N);

  // ---- phase 2: L = 2 layers; BN(l) fused into the next consumer ----
  const int PB = (N + 63) / 64;
  // l = 0 (acc1 dead before this dispatch -> P1/P2 overlay is legal)
  prep_P<false><<<PB, 256, 0, stream>>>(
      h, W1t, sb1, nullptr, nullptr, nullptr, nullptr, 0.0f, P1, P2, N);
  phase2_edge<<<1280, 256, 0, stream>>>(
      P1, P2, dstS, srcdtS, W2t, sb2, acc2, E, nwt);
  node_update_bn<true><<<1024, 256, 0, stream>>>(h, acc2, cntI,
                                                 bnsAll + 0, bnsAll + 64, N);
  // l = 1 (prep_P applies BN of layer 0 and writes post-BN h back)
  prep_P<true><<<PB, 256, 0, stream>>>(
      h, W1t + (size_t)64 * 128, sb1 + 64, bnsAll + 0, bnsAll + 64,
      bng, bnb, 1.0f / (float)N, P1, P2, N);
  phase2_edge<<<1280, 256, 0, stream>>>(
      P1, P2, dstS, srcdtS, W2t + (size_t)64 * 64, sb2 + 64, acc2, E, nwt);
  node_update_bn<false><<<1024, 256, 0, stream>>>(h, acc2, cntI,
                                                  bnsAll + 128, bnsAll + 192, N);

  // ---- classifier: BN of layer 1 fused into clf_mfma<4> staging ----
  const int CB = (B + 63) / 64;
  clf_mfma<4><<<CB, 256, 0, stream>>>(
      h, cW1t, cb1, z1, bnsAll + 256, bnsAll + 320,
      bnsAll + 128, bnsAll + 192, bng + 64, bnb + 64, 1.0f / (float)N, B);
  clf_mfma<2><<<CB, 256, 0, stream>>>(
      z1, cW2t, cb2, z2, bnsAll + 384, bnsAll + 448,
      bnsAll + 256, bnsAll + 320, cg1, cbb1, 1.0f / (float)B, B);
  clf_final<<<(B + 255) / 256, 256, 0, stream>>>(
      z2, cW3, cb3, bnsAll + 384, bnsAll + 448, cg2, cbb2,
      1.0f / (float)B, out, B);
}

// Round 12
// 777.292 us; speedup vs baseline: 1.0355x; 1.0271x over previous
//
#include <hip/hip_runtime.h>
#include <hip/hip_bf16.h>

// ---------------------------------------------------------------------------
// THEGCNModel — R28 (R27 + scatter∥prep grid-partition fusion):
//   * R27 confirmed the 796-798us best-known state. The untried lever:
//     dispatch overlap. k_scatter_x (85us, latency-bound, 8 VGPR, 38% occ)
//     and prep_all (~25us, streaming, independent buffers) ran back-to-back
//     on the serial stream. Fused: blocks [0,1024) = exact scatter body,
//     blocks [1024,1280) = exact prep body (65536 threads cover all one-shot
//     weight preps; grid-stride for xb/acc1). Prep hides in scatter's idle
//     issue slots.
//   * Everything else byte-identical to R27/R22: R19 edge bodies (2-deep
//     prefetch), phase1 768/(256,3), phase2 1280/(256,5), XCD dst-tiling,
//     full-wave cos, scalar walk, node_update_bn<ZERO>.
//   * Falsified (do not retry): phase1 occupancy bumps (L2 thrash), tile
//     pairing via by-ref lambdas (spill), node+prep fusion over uni (race),
//     scatter redesigns (vectorized/1-pass/bucket all = or worse than 85us).
// ---------------------------------------------------------------------------

typedef float  f32x4 __attribute__((ext_vector_type(4)));
typedef short  s16x8 __attribute__((ext_vector_type(8)));

__device__ __forceinline__ float tanh_factor(float u) {
  // 2*tanh(u)-1 == 1 - 4/(exp(2u)+1); rcp is 1-ulp approx (noise vs bf16)
  float e = __expf(2.0f * u);
  return fmaf(-4.0f, __builtin_amdgcn_rcpf(e + 1.0f), 1.0f);
}

__device__ __forceinline__ void atomic_add_f32(float* p, float v) {
  unsafeAtomicAdd(p, v);               // native global_atomic_add_f32
}

__device__ __forceinline__ unsigned short f2bf(float f) {
  __hip_bfloat16 b = __float2bfloat16(f);
  return *(unsigned short*)&b;
}
__device__ __forceinline__ float bf2f(unsigned short u) {
  unsigned int v = ((unsigned int)u) << 16;
  return *(float*)&v;
}

// ---------------------------------------------------------------------------
// Counting sort by dst: histogram -> scan -> expand(dstS) -> scatter(src,dts).
// ---------------------------------------------------------------------------
__global__ __launch_bounds__(256) void k_hist(
    const int* __restrict__ ei, int* __restrict__ cntI, int E)
{
  int e = blockIdx.x * 256 + threadIdx.x;
  if (e < E) atomicAdd(&cntI[__builtin_nontemporal_load(ei + E + e)], 1);
}

__global__ __launch_bounds__(256) void k_scan_block(
    const int* __restrict__ cntI, int* __restrict__ cursor,
    int* __restrict__ bsum, int N)
{
  __shared__ int s[256];
  const int t = threadIdx.x;
  int i = blockIdx.x * 256 + t;
  int v = (i < N) ? cntI[i] : 0;
  s[t] = v;
  for (int off = 1; off < 256; off <<= 1) {
    __syncthreads();
    int x = (t >= off) ? s[t - off] : 0;
    __syncthreads();
    s[t] += x;
  }
  __syncthreads();
  if (i < N) cursor[i] = s[t] - v;          // local exclusive
  if (t == 255) bsum[blockIdx.x] = s[255];
}

__global__ __launch_bounds__(512) void k_scan_bsum(int* __restrict__ bsum, int nb)
{
  __shared__ int s[512];
  const int t = threadIdx.x;
  int v = (t < nb) ? bsum[t] : 0;
  s[t] = v;
  for (int off = 1; off < 512; off <<= 1) {
    __syncthreads();
    int x = (t >= off) ? s[t - off] : 0;
    __syncthreads();
    s[t] += x;
  }
  __syncthreads();
  if (t < nb) bsum[t] = s[t] - v;           // exclusive
}

// fused: cursor += block offset (final rowPtr) AND expand dstS runs.
__global__ __launch_bounds__(256) void k_expand_add(
    int* __restrict__ cursor, const int* __restrict__ bsum,
    const int* __restrict__ cntI, int* __restrict__ dstS, int N)
{
  int n = blockIdx.x * 256 + threadIdx.x;
  if (n >= N) return;
  int cur = cursor[n] + bsum[blockIdx.x];
  cursor[n] = cur;
  int c = cntI[n];
  for (int i = 0; i < c; i++) dstS[cur + i] = n;
}

// ---------------------------------------------------------------------------
// Fused scatter ∥ prep (R28): blocks [0,1024) = XCD-partitioned scatter
// (exact R22 body); blocks [1024,1280) = prep_all body (weights, xb,
// acc1/bnsAll zero). The two halves touch disjoint buffers; prep hides
// under scatter's gather/atomic latency.
// ---------------------------------------------------------------------------
__global__ __launch_bounds__(256) void k_scatter_prep(
    const int* __restrict__ ei, const float* __restrict__ dts,
    int* __restrict__ cursor, int2* __restrict__ srcdtS, int E, int N,
    const float* __restrict__ x, const float* __restrict__ tW1,
    const float* __restrict__ tW2, const float* __restrict__ sW1,
    const float* __restrict__ sW2, const float* __restrict__ cW1,
    const float* __restrict__ cW2, unsigned short* __restrict__ xb,
    unsigned short* __restrict__ W1t1, unsigned short* __restrict__ W2t1,
    unsigned short* __restrict__ W1t, unsigned short* __restrict__ W2t,
    unsigned short* __restrict__ cW1t, unsigned short* __restrict__ cW2t,
    float* __restrict__ acc1, float* __restrict__ bnsAll)
{
  if (blockIdx.x < 1024) {
    // ---- scatter half (exact R22 k_scatter_x, nb = 128) ----
    const int g  = blockIdx.x & 7;         // XCD proxy
    const int bi = blockIdx.x >> 3;
    const int nb = 128;
    const int lo = (int)(((long long)N * g) >> 3);
    const int hi = (int)(((long long)N * (g + 1)) >> 3);
    for (int e = bi * 256 + threadIdx.x; e < E; e += nb * 256) {
      int d = __builtin_nontemporal_load(ei + E + e);
      if (d >= lo && d < hi) {
        int s = __builtin_nontemporal_load(ei + e);
        float dt = __builtin_nontemporal_load(dts + e);
        int pos = atomicAdd(&cursor[d], 1);
        srcdtS[pos] = make_int2(s, __float_as_int(dt));
      }
    }
  } else {
    // ---- prep half (exact prep_all body over a virtual 256-block grid) ----
    const int NPREP = 256;
    int i = (blockIdx.x - 1024) * 256 + threadIdx.x;   // 0..65535
    int totalX = N * 24;
    for (int idx = i; idx < totalX; idx += NPREP * 256) {
      int n = idx / 24, c = idx - n * 24;
      xb[idx] = (c < 17) ? f2bf(x[n * 17 + c]) : (unsigned short)0;
    }
    for (int idx = i; idx < N * 17; idx += NPREP * 256) acc1[idx] = 0.0f;
    if (i < 512) bnsAll[i] = 0.0f;
    if (i < 48 * 96) {
      int n = i / 96, k = i - n * 96;
      int src = (k < 17) ? k : (k >= 24 && k < 41) ? (k - 24 + 17)
              : (k >= 48 && k < 80) ? (k - 48 + 34) : -1;
      W1t1[i] = (n < 33 && src >= 0) ? f2bf(tW1[src * 33 + n]) : (unsigned short)0;
    }
    if (i < 32 * 64) {
      int n = i / 64, k = i - n * 64;
      W2t1[i] = (n < 17 && k < 33) ? f2bf(tW2[k * 17 + n]) : (unsigned short)0;
    }
    if (i < 2 * 64 * 128) {
      int l = i >> 13; int r = i & 8191; int n = r >> 7; int k = r & 127;
      W1t[i] = f2bf(sW1[((size_t)l * 128 + k) * 64 + n]);
    }
    if (i < 2 * 64 * 64) {
      int l = i >> 12; int r = i & 4095; int n = r >> 6; int k = r & 63;
      W2t[i] = f2bf(sW2[((size_t)l * 64 + k) * 64 + n]);
    }
    if (i < 64 * 64) {
      int c = i >> 6, k = i & 63;
      cW1t[i] = f2bf(cW1[k * 64 + c]);
    }
    if (i < 32 * 64) {
      int c = i >> 6, k = i & 63;
      cW2t[i] = f2bf(cW2[k * 32 + c]);
    }
  }
}

// ---------------------------------------------------------------------------
// Phase 1 edge kernel (MFMA, barrier-free wave-private 16-edge tiles).
// R22: R19 body (2-deep prefetch: idx(t+2)/payload(t+1)) at the low-FETCH
// config 768/(256,3).
// ---------------------------------------------------------------------------
__global__ __launch_bounds__(256, 3) void phase1_edge_mfma(
    const unsigned short* __restrict__ xb, const int* __restrict__ dstS,
    const int2* __restrict__ srcdtS, const float* __restrict__ freq,
    const float* __restrict__ phs,
    const unsigned short* __restrict__ W1t1, const float* __restrict__ b1,
    const unsigned short* __restrict__ W2t1, const float* __restrict__ b2,
    float* __restrict__ accum, int E, int nwt)
{
  __shared__ unsigned short sA[64][104];
  __shared__ unsigned short sHid[64][72];
  __shared__ float sRed[64][20];
  __shared__ int   sDst[64];

  const int t = threadIdx.x;
  const int wv = t >> 6, lane = t & 63, l16 = lane & 15, quad = lane >> 4;
  const int r0 = wv * 16;
  const int e_loc = lane >> 2, q = lane & 3;
  const int rr = r0 + e_loc;

  s16x8 w1f[3][3], w2f[2][2];
  float bias1[3], bias2[2];
#pragma unroll
  for (int cb = 0; cb < 3; cb++) {
    int n = cb * 16 + l16;
#pragma unroll
    for (int kb = 0; kb < 3; kb++)
      w1f[cb][kb] = *(const s16x8*)&W1t1[n * 96 + kb * 32 + quad * 8];
    bias1[cb] = (n < 33) ? b1[n] : 0.0f;
  }
#pragma unroll
  for (int cb = 0; cb < 2; cb++) {
    int n = cb * 16 + l16;
#pragma unroll
    for (int kb = 0; kb < 2; kb++)
      w2f[cb][kb] = *(const s16x8*)&W2t1[n * 64 + kb * 32 + quad * 8];
    bias2[cb] = (n < 17) ? b2[n] : 0.0f;
  }

  // loop-invariant rel coefficients: this lane covers k = q*8 .. q*8+7
  float frq[8], phv[8];
#pragma unroll
  for (int j = 0; j < 8; j++) {
    frq[j] = freq[q * 8 + j];
    phv[j] = phs[q * 8 + j];
  }

  // zero own-wave pad columns once
  for (int i = lane; i < 16 * 28; i += 64) {
    int rrz = r0 + i / 28, c = i % 28;
    int col = (c < 6) ? 18 + c : (c < 12) ? 42 + (c - 6) : 80 + (c - 12);
    sA[rrz][col] = 0;
  }
  for (int i = lane; i < 256; i += 64)
    sHid[r0 + (i >> 4)][48 + (i & 15)] = 0;

  // XCD dst-range tiling: group g = blockIdx&7 owns [nwt*g/8, nwt*(g+1)/8).
  const int g8   = blockIdx.x & 7;
  const int tLo  = (int)(((long long)nwt * g8) >> 3);
  const int tHi  = (int)(((long long)nwt * (g8 + 1)) >> 3);
  const int wLoc = (blockIdx.x >> 3) * 4 + wv;
  const int nwLoc = (gridDim.x >> 3) * 4;

  // -- 2-deep pipeline: idx for tile t+1 (idxN/dtN), payload for tile t --
  int idxN = 0; float dtN = 0.0f;
  int ndP = 0; uint4 xa0, xa1; unsigned int xa2 = 0; float dtP = 0.0f;
  auto issue_idx = [&](int tt) {
    int er = (tt << 4) + e_loc; if (er >= E) er = E - 1;
    int2 sd = srcdtS[er];
    idxN = q ? sd.x : dstS[er];
    dtN  = __int_as_float(sd.y);
  };
  auto issue_payload = [&]() {           // consumes idxN/dtN already in regs
    ndP = idxN; dtP = dtN;
    if (q < 2) {
      const unsigned short* src = &xb[(size_t)ndP * 24];
      xa0 = *(const uint4*)&src[0];
      xa1 = *(const uint4*)&src[8];
      xa2 = *(const unsigned int*)&src[16];
    }
  };
  {
    int t0 = tLo + wLoc; if (t0 >= nwt) t0 = nwt - 1;
    issue_idx(t0);
    issue_payload();
    int t1 = t0 + nwLoc; if (t1 >= tHi) t1 = t0;
    issue_idx(t1);
  }

  for (int tile = tLo + wLoc; tile < tHi; tile += nwLoc) {
    const int eb = tile << 4;

    // stage pipelined regs -> LDS (own rows only; same-wave ordering)
    if (q < 2) {
      if (!q) sDst[rr] = ndP;
      const int base = q ? 24 : 0;
      *(uint4*)&sA[rr][base]     = xa0;
      *(uint4*)&sA[rr][base + 8] = xa1;
      *(unsigned int*)&sA[rr][base + 16] = xa2;
    }
    // all 64 lanes: 8 rel values each (k = q*8 + j) — no divergent half-wave
    {
      unsigned short tmp[8] __attribute__((aligned(16)));
#pragma unroll
      for (int j = 0; j < 8; j++)
        tmp[j] = f2bf(__cosf(fmaf(dtP, frq[j], phv[j])));
      *(uint4*)&sA[rr][48 + q * 8] = *(const uint4*)&tmp[0];
    }

    // payload gather for t+1 (index already resident — no dependent wait);
    // then index fetch for t+2. Both hide under pass1/pass2/tanh/walk.
    issue_payload();
    { int nt = tile + 2 * nwLoc; issue_idx(nt < tHi ? nt : tile); }

    // pass1: hid = relu(A @ W1 + b1)   (own row r0+l16)
    f32x4 a1[3];
#pragma unroll
    for (int cb = 0; cb < 3; cb++)
      a1[cb] = (f32x4){bias1[cb], bias1[cb], bias1[cb], bias1[cb]};
#pragma unroll
    for (int kb = 0; kb < 3; kb++) {
      s16x8 aF = *(const s16x8*)&sA[r0 + l16][kb * 32 + quad * 8];
#pragma unroll
      for (int cb = 0; cb < 3; cb++)
        a1[cb] = __builtin_amdgcn_mfma_f32_16x16x32_bf16(aF, w1f[cb][kb], a1[cb], 0, 0, 0);
    }
#pragma unroll
    for (int cb = 0; cb < 3; cb++)
#pragma unroll
      for (int reg = 0; reg < 4; reg++)
        sHid[r0 + quad * 4 + reg][cb * 16 + l16] = f2bf(fmaxf(a1[cb][reg], 0.0f));

    // pass2: u = hid @ W2 + b2
    f32x4 a2[2];
#pragma unroll
    for (int cb = 0; cb < 2; cb++)
      a2[cb] = (f32x4){bias2[cb], bias2[cb], bias2[cb], bias2[cb]};
#pragma unroll
    for (int kb = 0; kb < 2; kb++) {
      s16x8 aF = *(const s16x8*)&sHid[r0 + l16][kb * 32 + quad * 8];
#pragma unroll
      for (int cb = 0; cb < 2; cb++)
        a2[cb] = __builtin_amdgcn_mfma_f32_16x16x32_bf16(aF, w2f[cb][kb], a2[cb], 0, 0, 0);
    }

    // f -> sRed (own rows)
#pragma unroll
    for (int reg = 0; reg < 4; reg++) {
      int row = r0 + quad * 4 + reg;
      bool ok = (eb + quad * 4 + reg < E);
      sRed[row][l16] = ok ? tanh_factor(a2[0][reg]) : 0.0f;
      if (l16 == 0) sRed[row][16] = ok ? tanh_factor(a2[1][reg]) : 0.0f;
    }

    // wave-local segmented walk: lanes 0..16, col = lane, own 16 rows.
    if (lane < 17) {
      int col = lane;
      float run = 0.0f;
      int cur = __builtin_amdgcn_readfirstlane(sDst[r0]);
#pragma unroll
      for (int k = 0; k < 16; k++) {
        int d = __builtin_amdgcn_readfirstlane(sDst[r0 + k]);
        float v = sRed[r0 + k][col];
        if (d != cur) {
          atomic_add_f32(&accum[(size_t)cur * 17 + col], run);
          run = 0.0f; cur = d;
        }
        run += v;
      }
      atomic_add_f32(&accum[(size_t)cur * 17 + col], run);
    }
  }
}

// ---------------------------------------------------------------------------
// Phase 1 node kernel: h[n] = (x[n] * (1 + acc/max(cnt,1))) @ projW + projb.
// Also zeroes acc2 (replaces a 25.6MB memset dispatch).
// ---------------------------------------------------------------------------
__global__ __launch_bounds__(256) void phase1_node(
    const float* __restrict__ x, const float* __restrict__ acc1,
    const int* __restrict__ cntI, const float* __restrict__ Wp,
    const float* __restrict__ bp, float* __restrict__ h,
    float* __restrict__ acc2, int N)
{
  __shared__ float s0[4][20];
  const int t = threadIdx.x;
  const int nb = blockIdx.x << 2;
  if (t < 68) {
    int nl = t / 17, c = t % 17;
    int n = nb + nl;
    float v = 0.0f;
    if (n < N) {
      float cnt = fmaxf((float)cntI[n], 1.0f);
      v = x[n * 17 + c] * (1.0f + acc1[n * 17 + c] / cnt);
    }
    s0[nl][c] = v;
  }
  __syncthreads();
  int nl = t >> 6, j = t & 63;
  int n = nb + nl;
  if (n < N) {
    float acc = bp[j];
#pragma unroll
    for (int c = 0; c < 17; c++) acc = fmaf(s0[nl][c], Wp[c * 64 + j], acc);
    h[n * 64 + j] = acc;
    acc2[n * 64 + j] = 0.0f;
  }
}

// ---------------------------------------------------------------------------
// prep_P<DO_BN>: P1[n] = h'[n]@W1a + b1, P2[n] = h'[n]@W1b where
// h' = DO_BN ? relu(BN(h)) : h. DO_BN also writes h' back.
// ---------------------------------------------------------------------------
template <bool DO_BN>
__global__ void prep_P(
    float* __restrict__ h, const unsigned short* __restrict__ W1t,
    const float* __restrict__ b1,
    const float* __restrict__ bns, const float* __restrict__ bnq,
    const float* __restrict__ gam, const float* __restrict__ bet, float invR,
    unsigned short* __restrict__ P1, unsigned short* __restrict__ P2, int N)
{
  __shared__ unsigned short sH[64][72];
  __shared__ float sM[64], sS[64], sB[64];
  const int t = threadIdx.x;
  const int wv = t >> 6, lane = t & 63, l16 = lane & 15, quad = lane >> 4;
  const int nb = blockIdx.x << 6;

  if (DO_BN) {
    if (t < 64) {
      float m = bns[t] * invR;
      float var = bnq[t] * invR - m * m;
      sM[t] = m;
      sS[t] = gam[t] * rsqrtf(var + 1e-5f);
      sB[t] = bet[t];
    }
    __syncthreads();
  }

#pragma unroll
  for (int i = 0; i < 4; i++) {
    int g = t + i * 256;
    int r = g >> 4, c4 = (g & 15) << 2;
    int n0 = nb + r;
    bool valid = (n0 < N);
    int n = valid ? n0 : N - 1;
    float4 v = *(const float4*)&h[(size_t)n * 64 + c4];
    if (DO_BN) {
      v.x = fmaxf(fmaf(v.x - sM[c4 + 0], sS[c4 + 0], sB[c4 + 0]), 0.0f);
      v.y = fmaxf(fmaf(v.y - sM[c4 + 1], sS[c4 + 1], sB[c4 + 1]), 0.0f);
      v.z = fmaxf(fmaf(v.z - sM[c4 + 2], sS[c4 + 2], sB[c4 + 2]), 0.0f);
      v.w = fmaxf(fmaf(v.w - sM[c4 + 3], sS[c4 + 3], sB[c4 + 3]), 0.0f);
      if (valid) *(float4*)&h[(size_t)n0 * 64 + c4] = v;
    }
    ushort4 o = { f2bf(v.x), f2bf(v.y), f2bf(v.z), f2bf(v.w) };
    *(ushort4*)&sH[r][c4] = o;
  }
  __syncthreads();

  const int n = nb + wv * 16 + l16;
#pragma unroll
  for (int half = 0; half < 2; half++) {
    f32x4 acc[4];
#pragma unroll
    for (int cb = 0; cb < 4; cb++) {
      if (half == 0) {
        float4 bv = *(const float4*)&b1[cb * 16 + quad * 4];
        acc[cb] = (f32x4){bv.x, bv.y, bv.z, bv.w};
      } else {
        acc[cb] = (f32x4){0.0f, 0.0f, 0.0f, 0.0f};
      }
    }
#pragma unroll
    for (int kb = 0; kb < 2; kb++) {
      s16x8 bF = *(const s16x8*)&sH[wv * 16 + l16][kb * 32 + quad * 8];
#pragma unroll
      for (int cb = 0; cb < 4; cb++) {
        s16x8 aF = *(const s16x8*)&W1t[(cb * 16 + l16) * 128 + half * 64 + kb * 32 + quad * 8];
        acc[cb] = __builtin_amdgcn_mfma_f32_16x16x32_bf16(aF, bF, acc[cb], 0, 0, 0);
      }
    }
    if (n < N) {
      unsigned short* P = half ? P2 : P1;
#pragma unroll
      for (int cb = 0; cb < 4; cb++) {
        ushort4 o = { f2bf(acc[cb][0]), f2bf(acc[cb][1]),
                      f2bf(acc[cb][2]), f2bf(acc[cb][3]) };
        *(ushort4*)&P[(size_t)n * 64 + cb * 16 + quad * 4] = o;
      }
    }
  }
}

// ---------------------------------------------------------------------------
// Phase 2 edge kernel — barrier-free wave-private 16-edge tiles.
// R19 exact: bounds(256,5), grid 1280, 2-deep prefetch idx(t+2)/payload(t+1).
// ---------------------------------------------------------------------------
__global__ __launch_bounds__(256, 5) void phase2_edge(
    const unsigned short* __restrict__ P1, const unsigned short* __restrict__ P2,
    const int* __restrict__ dstS, const int2* __restrict__ srcdtS,
    const unsigned short* __restrict__ W2t, const float* __restrict__ b2,
    float* __restrict__ accum, int E, int nwt)
{
  __shared__ unsigned short sA[64][136];   // [edge][0:64]=P1[dst], [64:128]=P2[src]
  __shared__ int sDst[64];
  float* sRedF = (float*)&sA[0][0];        // aliased 64x68 f32 (same stride 272B)

  const int t = threadIdx.x;
  const int wv = t >> 6, lane = t & 63, l16 = lane & 15, quad = lane >> 4;
  const int r0 = wv * 16;

  s16x8 w2f[4][2];
  f32x4 bias2v[4];
#pragma unroll
  for (int cb = 0; cb < 4; cb++) {
#pragma unroll
    for (int kb = 0; kb < 2; kb++)
      w2f[cb][kb] = *(const s16x8*)&W2t[(cb * 16 + l16) * 64 + kb * 32 + quad * 8];
    float4 bv = *(const float4*)&b2[cb * 16 + quad * 4];
    bias2v[cb] = (f32x4){bv.x, bv.y, bv.z, bv.w};
  }

  const int eRow = r0 + l16;

  const int e_loc = lane >> 2, q = lane & 3;
  const int rr = r0 + e_loc;
  const unsigned short* const Pb = (q < 2) ? P1 : P2;
  const int cb0 = q * 32;
  const size_t sub = (size_t)((q & 1) * 32);

  // XCD dst-range tiling: group g = blockIdx&7 owns [nwt*g/8, nwt*(g+1)/8).
  const int g8   = blockIdx.x & 7;
  const int tLo  = (int)(((long long)nwt * g8) >> 3);
  const int tHi  = (int)(((long long)nwt * (g8 + 1)) >> 3);
  const int wLoc = (blockIdx.x >> 3) * 4 + wv;
  const int nwLoc = (gridDim.x >> 3) * 4;

  // -- 2-deep pipeline: idx for tile t+1, payload (64B row-quarter) for t --
  int idxN = 0;
  int ndP = 0; uint4 pA, pB, pC, pD;
  auto issue_idx = [&](int tt) {
    int er = (tt << 4) + e_loc; if (er >= E) er = E - 1;
    idxN = (q < 2) ? dstS[er] : srcdtS[er].x;
  };
  auto issue_payload = [&]() {           // consumes idxN already in regs
    ndP = idxN;
    const unsigned short* src = Pb + (size_t)ndP * 64 + sub;
    pA = *(const uint4*)&src[0];
    pB = *(const uint4*)&src[8];
    pC = *(const uint4*)&src[16];
    pD = *(const uint4*)&src[24];
  };
  {
    int t0 = tLo + wLoc; if (t0 >= nwt) t0 = nwt - 1;
    issue_idx(t0);
    issue_payload();
    int t1 = t0 + nwLoc; if (t1 >= tHi) t1 = t0;
    issue_idx(t1);
  }

  for (int tile = tLo + wLoc; tile < tHi; tile += nwLoc) {
    const int eb = tile << 4;

    // stage pipelined regs -> LDS (own rows only; same-wave ordering)
    if (q == 0) sDst[rr] = ndP;
    *(uint4*)&sA[rr][cb0]      = pA;
    *(uint4*)&sA[rr][cb0 + 8]  = pB;
    *(uint4*)&sA[rr][cb0 + 16] = pC;
    *(uint4*)&sA[rr][cb0 + 24] = pD;

    // payload gather for t+1 (index already resident), then idx for t+2.
    issue_payload();
    { int nt = tile + 2 * nwLoc; issue_idx(nt < tHi ? nt : tile); }

    // hidden B-frags: relu(P1+P2), packed bf16 (own row)
    s16x8 hidf[2];
#pragma unroll
    for (int kb = 0; kb < 2; kb++) {
      s16x8 x1 = *(const s16x8*)&sA[eRow][kb * 32 + quad * 8];
      s16x8 x2 = *(const s16x8*)&sA[eRow][64 + kb * 32 + quad * 8];
      s16x8 hf;
#pragma unroll
      for (int j = 0; j < 8; j++) {
        float a = bf2f((unsigned short)x1[j]);
        float b = bf2f((unsigned short)x2[j]);
        hf[j] = (short)f2bf(fmaxf(a + b, 0.0f));
      }
      hidf[kb] = hf;
    }

    // u^T[n2][edge] = W2t @ hidden^T + b2
    f32x4 acc[4];
#pragma unroll
    for (int cb = 0; cb < 4; cb++) acc[cb] = bias2v[cb];
#pragma unroll
    for (int kb = 0; kb < 2; kb++)
#pragma unroll
      for (int cb = 0; cb < 4; cb++)
        acc[cb] = __builtin_amdgcn_mfma_f32_16x16x32_bf16(w2f[cb][kb], hidf[kb], acc[cb], 0, 0, 0);

    // f = 2*tanh(u)-1 -> sRedF (own rows; same-wave ordering)
    bool ok = (eb + l16 < E);
#pragma unroll
    for (int cb = 0; cb < 4; cb++) {
      f32x4 f;
#pragma unroll
      for (int reg = 0; reg < 4; reg++)
        f[reg] = ok ? tanh_factor(acc[cb][reg]) : 0.0f;
      *(f32x4*)&sRedF[eRow * 68 + cb * 16 + quad * 4] = f;
    }

    // wave-local segmented walk: lane = col, own 16 rows.
    {
      float run = 0.0f;
      int cur = __builtin_amdgcn_readfirstlane(sDst[r0]);
#pragma unroll
      for (int k = 0; k < 16; k++) {
        int d = __builtin_amdgcn_readfirstlane(sDst[r0 + k]);
        float v = sRedF[(r0 + k) * 68 + lane];
        if (d != cur) {                       // scalar branch
          atomic_add_f32(&accum[(size_t)cur * 64 + lane], run);
          run = 0.0f; cur = d;
        }
        run += v;
      }
      atomic_add_f32(&accum[(size_t)cur * 64 + lane], run);
    }
  }
}

// ---------------------------------------------------------------------------
// Node update + BN statistics. ZERO: re-zero accum for the next layer
// (skipped on the last layer — saves a 25.6MB write).
// ---------------------------------------------------------------------------
template <bool ZERO>
__global__ __launch_bounds__(256) void node_update_bn(
    float* __restrict__ h, float* __restrict__ accum,
    const int* __restrict__ cntI, float* __restrict__ bns,
    float* __restrict__ bnq, int N)
{
  const int t = threadIdx.x;
  float ls = 0.0f, lq = 0.0f;
  int total = N * 64;
  for (int idx = blockIdx.x * 256 + t; idx < total; idx += gridDim.x * 256) {
    int n = idx >> 6;
    float cnt = fmaxf((float)cntI[n], 1.0f);
    float v = h[idx] * (1.0f + accum[idx] / cnt);
    if (ZERO) accum[idx] = 0.0f;       // ready for next layer's scatter
    h[idx] = v;
    ls += v; lq += v * v;
  }
  __shared__ float ss[256], sq[256];
  ss[t] = ls; sq[t] = lq;
  __syncthreads();
  if (t < 64) {
    float s = ss[t] + ss[t + 64] + ss[t + 128] + ss[t + 192];
    float q = sq[t] + sq[t + 64] + sq[t + 128] + sq[t + 192];
    atomic_add_f32(&bns[t], s);
    atomic_add_f32(&bnq[t], q);
  }
}

// ---------------------------------------------------------------------------
// Classifier MFMA with input-BN fused at staging.
// ---------------------------------------------------------------------------
template <int NCB>
__global__ __launch_bounds__(256) void clf_mfma(
    const float* __restrict__ in, const unsigned short* __restrict__ Wt,
    const float* __restrict__ bias, float* __restrict__ z,
    float* __restrict__ bns, float* __restrict__ bnq,
    const float* __restrict__ ibns, const float* __restrict__ ibnq,
    const float* __restrict__ igam, const float* __restrict__ ibet,
    float iinvR, int rows)
{
  __shared__ unsigned short sIn[64][72];
  __shared__ float sM[64], sS[64], sB[64];
  const int t = threadIdx.x;
  const int wv = t >> 6, lane = t & 63, l16 = lane & 15, quad = lane >> 4;
  const int nb = blockIdx.x << 6;

  if (t < 64) {
    float m = ibns[t] * iinvR;
    float var = ibnq[t] * iinvR - m * m;
    sM[t] = m;
    sS[t] = igam[t] * rsqrtf(var + 1e-5f);
    sB[t] = ibet[t];
  }

  s16x8 wf[NCB][2];
  f32x4 bv[NCB];
#pragma unroll
  for (int cb = 0; cb < NCB; cb++) {
#pragma unroll
    for (int kb = 0; kb < 2; kb++)
      wf[cb][kb] = *(const s16x8*)&Wt[(cb * 16 + l16) * 64 + kb * 32 + quad * 8];
    float4 b4 = *(const float4*)&bias[cb * 16 + quad * 4];
    bv[cb] = (f32x4){b4.x, b4.y, b4.z, b4.w};
  }
  __syncthreads();   // sM/sS/sB visible

#pragma unroll
  for (int i = 0; i < 4; i++) {
    int g = t + i * 256;
    int r = g >> 4, c4 = (g & 15) << 2;
    int n = nb + r; if (n >= rows) n = rows - 1;
    float4 v = *(const float4*)&in[(size_t)n * 64 + c4];
    v.x = fmaxf(fmaf(v.x - sM[c4 + 0], sS[c4 + 0], sB[c4 + 0]), 0.0f);
    v.y = fmaxf(fmaf(v.y - sM[c4 + 1], sS[c4 + 1], sB[c4 + 1]), 0.0f);
    v.z = fmaxf(fmaf(v.z - sM[c4 + 2], sS[c4 + 2], sB[c4 + 2]), 0.0f);
    v.w = fmaxf(fmaf(v.w - sM[c4 + 3], sS[c4 + 3], sB[c4 + 3]), 0.0f);
    ushort4 o = { f2bf(v.x), f2bf(v.y), f2bf(v.z), f2bf(v.w) };
    *(ushort4*)&sIn[r][c4] = o;
  }
  __syncthreads();

  const int n = nb + wv * 16 + l16;
  const bool ok = (n < rows);
  f32x4 acc[NCB];
#pragma unroll
  for (int cb = 0; cb < NCB; cb++) acc[cb] = bv[cb];
#pragma unroll
  for (int kb = 0; kb < 2; kb++) {
    s16x8 bF = *(const s16x8*)&sIn[wv * 16 + l16][kb * 32 + quad * 8];
#pragma unroll
    for (int cb = 0; cb < NCB; cb++)
      acc[cb] = __builtin_amdgcn_mfma_f32_16x16x32_bf16(wf[cb][kb], bF, acc[cb], 0, 0, 0);
  }

  // store z (f32) + per-col stats reduced over the wave's 16 rows
#pragma unroll
  for (int cb = 0; cb < NCB; cb++) {
    if (ok)
      *(float4*)&z[(size_t)n * (NCB * 16) + cb * 16 + quad * 4] =
          make_float4(acc[cb][0], acc[cb][1], acc[cb][2], acc[cb][3]);
    f32x4 s, q;
#pragma unroll
    for (int reg = 0; reg < 4; reg++) {
      float v = ok ? acc[cb][reg] : 0.0f;
      s[reg] = v; q[reg] = v * v;
    }
#pragma unroll
    for (int m = 1; m < 16; m <<= 1) {
#pragma unroll
      for (int reg = 0; reg < 4; reg++) {
        s[reg] += __shfl_xor(s[reg], m);
        q[reg] += __shfl_xor(q[reg], m);
      }
    }
    if (l16 == 0) {
#pragma unroll
      for (int reg = 0; reg < 4; reg++) {
        int col = cb * 16 + quad * 4 + reg;
        atomic_add_f32(&bns[col], s[reg]);
        atomic_add_f32(&bnq[col], q[reg]);
      }
    }
  }
}

// clf_final with fused input BN (slot stats over 32 cols).
__global__ __launch_bounds__(256) void clf_final(
    const float* __restrict__ z2, const float* __restrict__ W3,
    const float* __restrict__ b3,
    const float* __restrict__ ibns, const float* __restrict__ ibnq,
    const float* __restrict__ igam, const float* __restrict__ ibet,
    float iinvR, float* __restrict__ out, int rows)
{
  __shared__ float sM[32], sS[32], sB[32];
  const int t = threadIdx.x;
  if (t < 32) {
    float m = ibns[t] * iinvR;
    float var = ibnq[t] * iinvR - m * m;
    sM[t] = m;
    sS[t] = igam[t] * rsqrtf(var + 1e-5f);
    sB[t] = ibet[t];
  }
  __syncthreads();
  int n = blockIdx.x * 256 + t;
  if (n >= rows) return;
  float acc = b3[0];
#pragma unroll
  for (int k = 0; k < 32; k++) {
    float v = fmaxf(fmaf(z2[n * 32 + k] - sM[k], sS[k], sB[k]), 0.0f);
    acc = fmaf(v, W3[k], acc);
  }
  out[n] = acc;
}

// ---------------------------------------------------------------------------
extern "C" void kernel_launch(void* const* d_in, const int* in_sizes, int n_in,
                              void* d_out, int out_size, void* d_ws, size_t ws_size,
                              hipStream_t stream)
{
  const float* x    = (const float*)d_in[0];
  const int*   ei   = (const int*)  d_in[1];
  const float* dts  = (const float*)d_in[2];
  const float* freq = (const float*)d_in[4];
  const float* phs  = (const float*)d_in[5];
  const float* tW1  = (const float*)d_in[6];
  const float* tb1  = (const float*)d_in[7];
  const float* tW2  = (const float*)d_in[8];
  const float* tb2  = (const float*)d_in[9];
  const float* pW   = (const float*)d_in[10];
  const float* pb   = (const float*)d_in[11];
  const float* sW1  = (const float*)d_in[12];
  const float* sb1  = (const float*)d_in[13];
  const float* sW2  = (const float*)d_in[14];
  const float* sb2  = (const float*)d_in[15];
  const float* bng  = (const float*)d_in[16];
  const float* bnb  = (const float*)d_in[17];
  const float* cW1  = (const float*)d_in[18];
  const float* cb1  = (const float*)d_in[19];
  const float* cg1  = (const float*)d_in[20];
  const float* cbb1 = (const float*)d_in[21];
  const float* cW2  = (const float*)d_in[22];
  const float* cb2  = (const float*)d_in[23];
  const float* cg2  = (const float*)d_in[24];
  const float* cbb2 = (const float*)d_in[25];
  const float* cW3  = (const float*)d_in[26];
  const float* cb3  = (const float*)d_in[27];
  float* out = (float*)d_out;

  const int N = in_sizes[0] / 17;
  const int E = in_sizes[1] / 2;
  const int B = out_size;

  // ---- workspace layout (byte offsets, union region for phase-local data) --
  char* base = (char*)d_ws;
  size_t off = 0;
  float* h    = (float*)(base + off); off += (size_t)N * 64 * 4;
  float* acc2 = (float*)(base + off); off += (size_t)N * 64 * 4;
  char*  uni  = base + off;           off += (size_t)N * 64 * 4;  // union
  float* bnsAll = (float*)(base + off); off += 8 * 64 * 4;        // 4 slot pairs
  unsigned short* W1t = (unsigned short*)(base + off); off += 2 * 64 * 128 * 2;
  unsigned short* W2t = (unsigned short*)(base + off); off += 2 * 64 * 64 * 2;
  unsigned short* cW1t = (unsigned short*)(base + off); off += 64 * 64 * 2;
  unsigned short* cW2t = (unsigned short*)(base + off); off += 32 * 64 * 2;
  int* cntI   = (int*)(base + off); off += (size_t)N * 4;
  int* cursor = (int*)(base + off); off += (size_t)N * 4;
  int* bsum   = (int*)(base + off); off += 512 * 4;
  int* dstS   = (int*)(base + off); off += (size_t)E * 4;
  off = (off + 15) & ~(size_t)15;
  int2* srcdtS = (int2*)(base + off); off += (size_t)E * 8;
  size_t needed = off;
  if (ws_size < needed) return;  // fail visibly (output stays poisoned)

  // union members (phase1 | phase2 | classifier — lifetimes disjoint)
  float* acc1 = (float*)uni;                                     // N*17 f32
  unsigned short* xb   = (unsigned short*)(uni + (size_t)N * 17 * 4); // N*24
  unsigned short* W1t1 = xb + (size_t)N * 24;                    // 48*96
  unsigned short* W2t1 = W1t1 + 48 * 96;                         // 32*64
  unsigned short* P1 = (unsigned short*)uni;                     // N*64
  unsigned short* P2 = P1 + (size_t)N * 64;                      // N*64
  float* z1 = (float*)uni;                                       // B*64
  float* z2 = z1 + (size_t)B * 64;                               // B*32

  const int nwt = (E + 15) / 16;
  const int NB = (N + 255) / 256;
  if (NB > 512) return;

  // ---- init: cntI only (acc1/bnsAll zeroed inside k_scatter_prep) ----
  hipMemsetAsync(cntI, 0, (size_t)N * 4, stream);

  // ---- counting sort by dst + (scatter ∥ weight/x prep) ----
  k_hist<<<(E + 255) / 256, 256, 0, stream>>>(ei, cntI, E);
  k_scan_block<<<NB, 256, 0, stream>>>(cntI, cursor, bsum, N);
  k_scan_bsum<<<1, 512, 0, stream>>>(bsum, NB);
  k_expand_add<<<NB, 256, 0, stream>>>(cursor, bsum, cntI, dstS, N);
  k_scatter_prep<<<1280, 256, 0, stream>>>(
      ei, dts, cursor, srcdtS, E, N,
      x, tW1, tW2, sW1, sW2, cW1, cW2, xb, W1t1, W2t1, W1t, W2t,
      cW1t, cW2t, acc1, bnsAll);

  // ---- phase 1 (768/(256,3) low-FETCH config, 2-deep prefetch) ----
  phase1_edge_mfma<<<768, 256, 0, stream>>>(
      xb, dstS, srcdtS, freq, phs, W1t1, tb1, W2t1, tb2, acc1, E, nwt);
  phase1_node<<<(N + 3) / 4, 256, 0, stream>>>(x, acc1, cntI, pW, pb, h, acc2, N);

  // ---- phase 2: L = 2 layers; BN(l) fused into the next consumer ----
  const int PB = (N + 63) / 64;
  // l = 0 (acc1 dead before this dispatch -> P1/P2 overlay is legal)
  prep_P<false><<<PB, 256, 0, stream>>>(
      h, W1t, sb1, nullptr, nullptr, nullptr, nullptr, 0.0f, P1, P2, N);
  phase2_edge<<<1280, 256, 0, stream>>>(
      P1, P2, dstS, srcdtS, W2t, sb2, acc2, E, nwt);
  node_update_bn<true><<<1024, 256, 0, stream>>>(h, acc2, cntI,
                                                 bnsAll + 0, bnsAll + 64, N);
  // l = 1 (prep_P applies BN of layer 0 and writes post-BN h back)
  prep_P<true><<<PB, 256, 0, stream>>>(
      h, W1t + (size_t)64 * 128, sb1 + 64, bnsAll + 0, bnsAll + 64,
      bng, bnb, 1.0f / (float)N, P1, P2, N);
  phase2_edge<<<1280, 256, 0, stream>>>(
      P1, P2, dstS, srcdtS, W2t + (size_t)64 * 64, sb2 + 64, acc2, E, nwt);
  node_update_bn<false><<<1024, 256, 0, stream>>>(h, acc2, cntI,
                                                  bnsAll + 128, bnsAll + 192, N);

  // ---- classifier: BN of layer 1 fused into clf_mfma<4> staging ----
  const int CB = (B + 63) / 64;
  clf_mfma<4><<<CB, 256, 0, stream>>>(
      h, cW1t, cb1, z1, bnsAll + 256, bnsAll + 320,
      bnsAll + 128, bnsAll + 192, bng + 64, bnb + 64, 1.0f / (float)N, B);
  clf_mfma<2><<<CB, 256, 0, stream>>>(
      z1, cW2t, cb2, z2, bnsAll + 384, bnsAll + 448,
      bnsAll + 256, bnsAll + 320, cg1, cbb1, 1.0f / (float)B, B);
  clf_final<<<(B + 255) / 256, 256, 0, stream>>>(
      z2, cW3, cb3, bnsAll + 384, bnsAll + 448, cg2, cbb2,
      1.0f / (float)B, out, B);
}